// Round 4
// baseline (266.371 us; speedup 1.0000x reference)
//
#include <hip/hip_runtime.h>

// dims
#define L_DIM 1024
#define E_DIM 1024
#define NB 4
#define H_NUM 16
#define HD_DIM 64
#define T_TOK 4096   // L*NB
#define NHB 64       // NB*H_NUM

typedef float f32x4 __attribute__((ext_vector_type(4)));
typedef unsigned short u16x8 __attribute__((ext_vector_type(8)));
typedef unsigned short u16x4 __attribute__((ext_vector_type(4)));
typedef __bf16 bf16x8 __attribute__((ext_vector_type(8)));

__device__ inline unsigned short f2bf(float f) {
  unsigned int u = __builtin_bit_cast(unsigned int, f);
  u += 0x7FFFu + ((u >> 16) & 1u);
  return (unsigned short)(u >> 16);
}
__device__ inline f32x4 mfma16(u16x8 a, u16x8 b, f32x4 c) {
  return __builtin_amdgcn_mfma_f32_16x16x32_bf16(
      __builtin_bit_cast(bf16x8, a), __builtin_bit_cast(bf16x8, b), c, 0, 0, 0);
}

// async global->LDS 16B copy
__device__ __forceinline__ void gl2lds16(const void* g, void* l) {
  auto gp = reinterpret_cast<const __attribute__((address_space(1))) unsigned int*>(
      reinterpret_cast<unsigned long long>(g));
  auto lp = reinterpret_cast<__attribute__((address_space(3))) unsigned int*>(
      static_cast<unsigned int>(reinterpret_cast<unsigned long long>(l)));
  __builtin_amdgcn_global_load_lds(gp, lp, 16, 0, 0);
}

// ---------------- K0: f32 -> bf16 cast (up to 4 arrays per launch) ----------------
__global__ __launch_bounds__(256) void cast_kernel(
    const float* __restrict__ s0, const float* __restrict__ s1,
    const float* __restrict__ s2, const float* __restrict__ s3,
    unsigned short* __restrict__ d0, unsigned short* __restrict__ d1,
    unsigned short* __restrict__ d2, unsigned short* __restrict__ d3,
    int n0, int n1, int n2, int n3) {
  const int y = blockIdx.y;
  const float* s = (y == 0) ? s0 : (y == 1) ? s1 : (y == 2) ? s2 : s3;
  unsigned short* d = (y == 0) ? d0 : (y == 1) ? d1 : (y == 2) ? d2 : d3;
  const int n = (y == 0) ? n0 : (y == 1) ? n1 : (y == 2) ? n2 : n3;
  int idx = (blockIdx.x * 256 + threadIdx.x) * 8;
  const int stride = gridDim.x * 256 * 8;
  for (; idx < n; idx += stride) {
    float4 a = *(const float4*)(s + idx);
    float4 b = *(const float4*)(s + idx + 4);
    u16x8 o = {f2bf(a.x), f2bf(a.y), f2bf(a.z), f2bf(a.w),
               f2bf(b.x), f2bf(b.y), f2bf(b.z), f2bf(b.w)};
    *(u16x8*)(d + idx) = o;
  }
}

// ---- shared GEMM staging: 128 rows x 32 k bf16 tile (8 KB), swizzled ----
__device__ __forceinline__ void stage_tile(const unsigned short* __restrict__ g,
                                           unsigned short* lbuf, int tid) {
  const int r = tid >> 2, c = tid & 3;
  const int sc = c ^ ((r ^ (r >> 2)) & 3);
  gl2lds16(g + (size_t)r * 1024 + sc * 8, lbuf + tid * 8);
  const int r2 = r + 64;
  gl2lds16(g + (size_t)r2 * 1024 + sc * 8, lbuf + (tid + 256) * 8);
}
__device__ __forceinline__ int frag_off(int r, int q) {
  return r * 32 + ((q ^ ((r ^ (r >> 2)) & 3)) << 3);
}

// ---------------- K1: packed QKV projection v2 ----------------
// 5-buffer ring / depth-3 prefetch / counted vmcnt (4 loads per step;
// 3 steps in flight -> vmcnt(12), tail 8/4/0) + bijective XCD swizzle.
__global__ __launch_bounds__(256) void qkv_gemm(
    const unsigned short* __restrict__ qb, const unsigned short* __restrict__ kb,
    const unsigned short* __restrict__ vb, const unsigned short* __restrict__ Wb,
    const float* __restrict__ bias, unsigned short* __restrict__ q_hm,
    unsigned short* __restrict__ k_hm, unsigned short* __restrict__ v_t) {
  __shared__ __align__(16) unsigned short As[5][4096];   // 40 KB
  __shared__ __align__(16) unsigned short Bs[5][4096];   // 40 KB
  const int tid = threadIdx.x;
  // XCD swizzle: 768 blocks = 8 XCDs x 96 contiguous tiles (B-panels L2-hot)
  const int flat = blockIdx.x + (blockIdx.y << 5) + (blockIdx.z << 8);
  const int nf = (flat & 7) * 96 + (flat >> 3);
  const int bm = nf & 31, bn = (nf >> 5) & 7, z = nf >> 8;
  const unsigned short* Ag = ((z == 0) ? qb : (z == 1) ? kb : vb) + (size_t)bm * 128 * 1024;
  const unsigned short* Bg = Wb + (size_t)z * 1048576 + (size_t)bn * 128 * 1024;
  const float* bc = bias + z * E_DIM;

  const int w = tid >> 6, lane = tid & 63;
  const int wm = w & 1, wn = w >> 1;
  const int quad = lane >> 4, l16 = lane & 15;

  f32x4 acc[4][4];
#pragma unroll
  for (int i = 0; i < 4; i++)
#pragma unroll
    for (int j = 0; j < 4; j++) { f32x4 zz = {0.f, 0.f, 0.f, 0.f}; acc[i][j] = zz; }

  // prologue: stage steps 0..2
#pragma unroll
  for (int t = 0; t < 3; t++) {
    stage_tile(Ag + t * 32, As[t], tid);
    stage_tile(Bg + t * 32, Bs[t], tid);
  }

  int cb = 0, sb = 3;
#pragma unroll 1
  for (int kk = 0; kk < 32; kk++) {
    if (kk < 29) {
      stage_tile(Ag + (kk + 3) * 32, As[sb], tid);
      stage_tile(Bg + (kk + 3) * 32, Bs[sb], tid);
      sb = (sb == 4) ? 0 : sb + 1;
      asm volatile("s_waitcnt vmcnt(12)" ::: "memory");
    } else if (kk == 29) {
      asm volatile("s_waitcnt vmcnt(8)" ::: "memory");
    } else if (kk == 30) {
      asm volatile("s_waitcnt vmcnt(4)" ::: "memory");
    } else {
      asm volatile("s_waitcnt vmcnt(0)" ::: "memory");
    }
    __builtin_amdgcn_s_barrier();
    asm volatile("" ::: "memory");
    u16x8 af[4], bfv[4];
#pragma unroll
    for (int mi = 0; mi < 4; mi++) {
      int r = wm * 64 + mi * 16 + l16;
      af[mi] = *(const u16x8*)&As[cb][frag_off(r, quad)];
    }
#pragma unroll
    for (int ni = 0; ni < 4; ni++) {
      int r = wn * 64 + ni * 16 + l16;
      bfv[ni] = *(const u16x8*)&Bs[cb][frag_off(r, quad)];
    }
#pragma unroll
    for (int mi = 0; mi < 4; mi++)
#pragma unroll
      for (int ni = 0; ni < 4; ni++)
        acc[mi][ni] = mfma16(af[mi], bfv[ni], acc[mi][ni]);
    cb = (cb == 4) ? 0 : cb + 1;
  }
#pragma unroll
  for (int ni = 0; ni < 4; ni++) {
    int col = bn * 128 + wn * 64 + ni * 16 + l16;
    float bv = bc[col];
    int h = col >> 6, d = col & 63;
#pragma unroll
    for (int mi = 0; mi < 4; mi++) {
#pragma unroll
      for (int r = 0; r < 4; r++) {
        int t = bm * 128 + wm * 64 + mi * 16 + quad * 4 + r;
        float v = acc[mi][ni][r] + bv;
        int nb = t & 3, pos = t >> 2;
        if (z == 0) {
          v *= 0.125f;
          q_hm[(size_t)((nb * 16 + h) * 1024 + pos) * 64 + d] = f2bf(v);
        } else if (z == 1) {
          k_hm[(size_t)((nb * 16 + h) * 1024 + pos) * 64 + d] = f2bf(v);
        } else {
          v_t[(size_t)((nb * 16 + h) * 64 + d) * 1024 + pos] = f2bf(v);
        }
      }
    }
  }
}

// ---------------- K3: attention core v4 (round-2 version, reverted) ----------------
__global__ __launch_bounds__(256, 2) void attn_kernel(
    const unsigned short* __restrict__ q_hm, const unsigned short* __restrict__ k_hm,
    const unsigned short* __restrict__ v_t, unsigned short* __restrict__ o_h,
    float* __restrict__ m_ws, float* __restrict__ r_ws) {
  __shared__ __align__(16) unsigned short stage[8][4096];   // 8 x 64x64 bf16 tiles
  __shared__ __align__(16) unsigned short pt[2][32][68];    // rotating P tile (l x s_local)
  __shared__ float red_m[4][32];
  __shared__ float red_s[4][32];

  const int tid = threadIdx.x;
  // XCD-bijective swizzle: linear id -> (xcd, local) -> contiguous heads per XCD
  const int flat = blockIdx.x + (blockIdx.y << 5);   // 0..2047
  const int nf = (flat & 7) * 256 + (flat >> 3);
  const int l0 = (nf & 31) * 32;
  const int b = nf >> 5;
  const int nb = b >> 4, h = b & 15;
  const int w = tid >> 6, lane = tid & 63;
  const int quad = lane >> 4, l16 = lane & 15;

  const int i1 = tid + 256;
  const int r0s = tid >> 3, c0s = tid & 7;
  const int r1s = i1 >> 3, c1s = i1 & 7;
  const int src0 = (c0s ^ (r0s & 7)) * 8;
  const int src1 = (c1s ^ (r1s & 7)) * 8;

  const unsigned short* kbase = k_hm + ((size_t)b << 16);
  const unsigned short* vbase = v_t + ((size_t)b << 16);

  // Q fragments for the 2 l-groups (B-operand, n = l) -- issue BEFORE staging
  u16x8 bq[2][2];
#pragma unroll
  for (int g = 0; g < 2; g++) {
    const unsigned short* qp =
        q_hm + ((size_t)(b * 1024 + l0 + g * 16 + l16) << 6) + quad * 8;
    bq[g][0] = *(const u16x8*)qp;
    bq[g][1] = *(const u16x8*)(qp + 32);
  }
  asm volatile("" ::: "memory");   // pin bq loads before the staging stream

  f32x4 acc[16][2];
#pragma unroll
  for (int j = 0; j < 16; j++)
#pragma unroll
    for (int g = 0; g < 2; g++) { f32x4 z = {0.f, 0.f, 0.f, 0.f}; acc[j][g] = z; }

  // prologue: stage K0..K2 (depth 3)
#pragma unroll
  for (int t = 0; t < 3; t++) {
    gl2lds16(kbase + ((size_t)(t * 64 + r0s) << 6) + src0, &stage[t][tid * 8]);
    gl2lds16(kbase + ((size_t)(t * 64 + r1s) << 6) + src1, &stage[t][i1 * 8]);
  }

  const int myrow = w * 16 + l16;
  const int sw0 = ((quad ^ (l16 & 7)) * 8);
  const int sw1 = (((quad + 4) ^ (l16 & 7)) * 8);

  // ---- phase 1: scores ----
#pragma unroll
  for (int j = 0; j < 16; j++) {
    if (j + 3 < 16) {
      gl2lds16(kbase + ((size_t)((j + 3) * 64 + r0s) << 6) + src0,
               &stage[(j + 3) & 7][tid * 8]);
      gl2lds16(kbase + ((size_t)((j + 3) * 64 + r1s) << 6) + src1,
               &stage[(j + 3) & 7][i1 * 8]);
    } else {
      // pipeline handoff: stage V tiles 0..2 for phase 3
      const int vt = j + 3 - 16;
      gl2lds16(vbase + ((size_t)r0s << 10) + vt * 64 + src0,
               &stage[(j + 3) & 7][tid * 8]);
      gl2lds16(vbase + ((size_t)r1s << 10) + vt * 64 + src1,
               &stage[(j + 3) & 7][i1 * 8]);
    }
    asm volatile("s_waitcnt vmcnt(6)" ::: "memory");  // tile j landed; 3 in flight
    __builtin_amdgcn_s_barrier();
    asm volatile("" ::: "memory");
    const unsigned short* kt = &stage[j & 7][myrow * 64];
    u16x8 ak0 = *(const u16x8*)(kt + sw0);
    u16x8 ak1 = *(const u16x8*)(kt + sw1);
    acc[j][0] = mfma16(ak0, bq[0][0], acc[j][0]);
    acc[j][0] = mfma16(ak1, bq[0][1], acc[j][0]);
    acc[j][1] = mfma16(ak0, bq[1][0], acc[j][1]);
    acc[j][1] = mfma16(ak1, bq[1][1], acc[j][1]);
  }

  // ---- phase 2: softmax stats (barriers wait lgkmcnt only; V0..V2 in flight) ----
  float lm0 = -3e38f, lm1 = -3e38f;
#pragma unroll
  for (int j = 0; j < 16; j++)
#pragma unroll
    for (int r = 0; r < 4; r++) {
      lm0 = fmaxf(lm0, acc[j][0][r]);
      lm1 = fmaxf(lm1, acc[j][1][r]);
    }
  lm0 = fmaxf(lm0, __shfl_xor(lm0, 16, 64));
  lm0 = fmaxf(lm0, __shfl_xor(lm0, 32, 64));
  lm1 = fmaxf(lm1, __shfl_xor(lm1, 16, 64));
  lm1 = fmaxf(lm1, __shfl_xor(lm1, 32, 64));
  if (lane < 16) { red_m[w][lane] = lm0; red_m[w][lane + 16] = lm1; }
  asm volatile("s_waitcnt lgkmcnt(0)" ::: "memory");
  __builtin_amdgcn_s_barrier();
  asm volatile("" ::: "memory");
  float m0 = fmaxf(fmaxf(red_m[0][l16], red_m[1][l16]),
                   fmaxf(red_m[2][l16], red_m[3][l16]));
  float m1 = fmaxf(fmaxf(red_m[0][l16 + 16], red_m[1][l16 + 16]),
                   fmaxf(red_m[2][l16 + 16], red_m[3][l16 + 16]));
  float mm = 0.f;
  if (tid < 32)
    mm = fmaxf(fmaxf(red_m[0][tid], red_m[1][tid]),
               fmaxf(red_m[2][tid], red_m[3][tid]));

  float ls0 = 0.f, ls1 = 0.f;
#pragma unroll
  for (int j = 0; j < 16; j++) {
#pragma unroll
    for (int r = 0; r < 4; r++) {
      float e0 = __expf(acc[j][0][r] - m0);
      float e1 = __expf(acc[j][1][r] - m1);
      acc[j][0][r] = e0;
      acc[j][1][r] = e1;
      ls0 += e0;
      ls1 += e1;
    }
  }
  ls0 += __shfl_xor(ls0, 16, 64);
  ls0 += __shfl_xor(ls0, 32, 64);
  ls1 += __shfl_xor(ls1, 16, 64);
  ls1 += __shfl_xor(ls1, 32, 64);
  if (lane < 16) { red_s[w][lane] = ls0; red_s[w][lane + 16] = ls1; }
  asm volatile("s_waitcnt lgkmcnt(0)" ::: "memory");
  __builtin_amdgcn_s_barrier();
  asm volatile("" ::: "memory");
  float rv0 = 1.0f / (red_s[0][l16] + red_s[1][l16] + red_s[2][l16] + red_s[3][l16]);
  float rv1 = 1.0f / (red_s[0][l16 + 16] + red_s[1][l16 + 16] +
                      red_s[2][l16 + 16] + red_s[3][l16 + 16]);
  float ssv = 1.f;
  if (tid < 32)
    ssv = red_s[0][tid] + red_s[1][tid] + red_s[2][tid] + red_s[3][tid];

  // ---- phase 3: PV with rotating P-tile transpose, depth-3 V pipeline ----
  {
    u16x4 p0 = {f2bf(acc[0][0][0]), f2bf(acc[0][0][1]), f2bf(acc[0][0][2]), f2bf(acc[0][0][3])};
    u16x4 p1 = {f2bf(acc[0][1][0]), f2bf(acc[0][1][1]), f2bf(acc[0][1][2]), f2bf(acc[0][1][3])};
    *(u16x4*)&pt[0][l16][w * 16 + quad * 4] = p0;
    *(u16x4*)&pt[0][16 + l16][w * 16 + quad * 4] = p1;
  }

  f32x4 oacc0 = {0.f, 0.f, 0.f, 0.f};
  f32x4 oacc1 = {0.f, 0.f, 0.f, 0.f};
#pragma unroll
  for (int j = 0; j < 16; j++) {
    if (j < 13) {
      const int t = j + 3;
      gl2lds16(vbase + ((size_t)r0s << 10) + t * 64 + src0, &stage[t & 7][tid * 8]);
      gl2lds16(vbase + ((size_t)r1s << 10) + t * 64 + src1, &stage[t & 7][i1 * 8]);
      asm volatile("s_waitcnt vmcnt(6) lgkmcnt(0)" ::: "memory");
    } else if (j == 13) {
      asm volatile("s_waitcnt vmcnt(4) lgkmcnt(0)" ::: "memory");
    } else if (j == 14) {
      asm volatile("s_waitcnt vmcnt(2) lgkmcnt(0)" ::: "memory");
    } else {
      asm volatile("s_waitcnt vmcnt(0) lgkmcnt(0)" ::: "memory");
    }
    __builtin_amdgcn_s_barrier();
    asm volatile("" ::: "memory");
    if (j < 15) {
      const int bf = (j + 1) & 1;
      u16x4 p0 = {f2bf(acc[j + 1][0][0]), f2bf(acc[j + 1][0][1]),
                  f2bf(acc[j + 1][0][2]), f2bf(acc[j + 1][0][3])};
      u16x4 p1 = {f2bf(acc[j + 1][1][0]), f2bf(acc[j + 1][1][1]),
                  f2bf(acc[j + 1][1][2]), f2bf(acc[j + 1][1][3])};
      *(u16x4*)&pt[bf][l16][w * 16 + quad * 4] = p0;
      *(u16x4*)&pt[bf][16 + l16][w * 16 + quad * 4] = p1;
    }
    const unsigned short* vt = &stage[j & 7][myrow * 64];
    u16x8 bv0 = *(const u16x8*)(vt + sw0);
    u16x8 bv1 = *(const u16x8*)(vt + sw1);
    u16x8 ap00 = *(const u16x8*)&pt[j & 1][l16][quad * 8];
    u16x8 ap01 = *(const u16x8*)&pt[j & 1][l16][32 + quad * 8];
    u16x8 ap10 = *(const u16x8*)&pt[j & 1][16 + l16][quad * 8];
    u16x8 ap11 = *(const u16x8*)&pt[j & 1][16 + l16][32 + quad * 8];
    oacc0 = mfma16(ap00, bv0, oacc0);
    oacc0 = mfma16(ap01, bv1, oacc0);
    oacc1 = mfma16(ap10, bv0, oacc1);
    oacc1 = mfma16(ap11, bv1, oacc1);
  }

  if (tid < 32) {
    m_ws[b * 1024 + l0 + tid] = mm;
    r_ws[b * 1024 + l0 + tid] = 1.0f / ssv;
  }

#pragma unroll
  for (int r = 0; r < 4; r++) {
    int lr = quad * 4 + r;
    float rr0 = __shfl(rv0, lr, 64);
    float rr1 = __shfl(rv1, lr, 64);
    int t0 = (l0 + lr) * 4 + nb;
    int t1 = (l0 + 16 + lr) * 4 + nb;
    o_h[((size_t)t0 << 10) + h * 64 + w * 16 + l16] = f2bf(oacc0[r] * rr0);
    o_h[((size_t)t1 << 10) + h * 64 + w * 16 + l16] = f2bf(oacc1[r] * rr1);
  }
}

// ---------------- K4: head-averaged attn + sigmoid weights v2 (unchanged) ----------------
__global__ __launch_bounds__(256, 2) void weights_kernel(
    const unsigned short* __restrict__ q_hm, const unsigned short* __restrict__ k_hm,
    const float* __restrict__ m_ws, const float* __restrict__ r_ws,
    float* __restrict__ attn_out, float* __restrict__ sig_out) {
  __shared__ __align__(16) unsigned short qs[4][4096];   // 32 KB
  __shared__ __align__(16) unsigned short ks[4][4096];   // 32 KB
  __shared__ float ml[16][64];
  __shared__ float rl[16][64];
  __shared__ float cl[16][64];

  const int tid = threadIdx.x;
  const int flat = blockIdx.x + (blockIdx.y << 4) + (blockIdx.z << 8);
  const int xcd = flat & 7, local = flat >> 3;           // local: 0..127
  const int nb = xcd >> 1;
  const int idx2 = ((xcd & 1) << 7) + local;             // 0..255
  const int l0 = (idx2 >> 4) << 6;
  const int s0 = (idx2 & 15) << 6;

  const int w = tid >> 6, lane = tid & 63;
  const int quad = lane >> 4, l16 = lane & 15;

  const int i1 = tid + 256;
  const int r0s = tid >> 3, c0s = tid & 7;
  const int r1s = i1 >> 3, c1s = i1 & 7;
  const int src0 = (c0s ^ (r0s & 7)) * 8;
  const int src1 = (c1s ^ (r1s & 7)) * 8;

  {
    int idx = tid * 4;
    int hh = idx >> 6, ii = idx & 63;
    int bb = nb * 16 + hh;
    float4 mv4 = *(const float4*)&m_ws[bb * 1024 + l0 + ii];
    float4 rv4 = *(const float4*)&r_ws[bb * 1024 + l0 + ii];
    *(float4*)&ml[hh][ii] = mv4;
    *(float4*)&rl[hh][ii] = rv4;
    float4 cv4 = {__expf(-mv4.x), __expf(-mv4.y), __expf(-mv4.z), __expf(-mv4.w)};
    *(float4*)&cl[hh][ii] = cv4;
  }

  const int sw0 = ((quad ^ (l16 & 7)) * 8);
  const int sw1 = (((quad + 4) ^ (l16 & 7)) * 8);

  auto stageQK = [&](int h) {
    const int bb = nb * 16 + h;
    const unsigned short* qb = q_hm + ((size_t)(bb * 1024 + l0) << 6);
    const unsigned short* kb = k_hm + ((size_t)(bb * 1024 + s0) << 6);
    const int bf = h & 3;
    gl2lds16(qb + (r0s << 6) + src0, &qs[bf][tid * 8]);
    gl2lds16(qb + (r1s << 6) + src1, &qs[bf][i1 * 8]);
    gl2lds16(kb + (r0s << 6) + src0, &ks[bf][tid * 8]);
    gl2lds16(kb + (r1s << 6) + src1, &ks[bf][i1 * 8]);
  };

  f32x4 accA[4], accS[4];
#pragma unroll
  for (int i = 0; i < 4; i++) {
    f32x4 zz = {0.f, 0.f, 0.f, 0.f};
    accA[i] = zz; accS[i] = zz;
  }

  stageQK(0);
  stageQK(1);
  asm volatile("s_waitcnt lgkmcnt(0)" ::: "memory");  // ml/rl/cl ds_writes done

  auto computeH = [&](int h) {
    const int bf = h & 3;
    const unsigned short* qt = &qs[bf][(w * 16 + l16) * 64];
    u16x8 a0 = *(const u16x8*)(qt + sw0);
    u16x8 a1 = *(const u16x8*)(qt + sw1);
    f32x4 mv = *(const f32x4*)&ml[h][w * 16 + quad * 4];
    f32x4 rv = *(const f32x4*)&rl[h][w * 16 + quad * 4];
    f32x4 cv = *(const f32x4*)&cl[h][w * 16 + quad * 4];
#pragma unroll
    for (int ni = 0; ni < 4; ni++) {
      const unsigned short* kt = &ks[bf][(ni * 16 + l16) * 64];
      u16x8 b0 = *(const u16x8*)(kt + sw0);
      u16x8 b1 = *(const u16x8*)(kt + sw1);
      f32x4 scv = {0.f, 0.f, 0.f, 0.f};
      scv = mfma16(a0, b0, scv);
      scv = mfma16(a1, b1, scv);
#pragma unroll
      for (int r = 0; r < 4; r++) {
        float e = __expf(scv[r] - mv[r]);
        accA[ni][r] += e * rv[r];
        accS[ni][r] += e * __builtin_amdgcn_rcpf(e + cv[r]);
      }
    }
  };

#pragma unroll 1
  for (int h = 0; h < 14; ++h) {
    stageQK(h + 2);
    asm volatile("s_waitcnt vmcnt(8)" ::: "memory");
    __builtin_amdgcn_s_barrier();
    asm volatile("" ::: "memory");
    computeH(h);
  }
  asm volatile("s_waitcnt vmcnt(4)" ::: "memory");
  __builtin_amdgcn_s_barrier();
  asm volatile("" ::: "memory");
  computeH(14);
  asm volatile("s_waitcnt vmcnt(0)" ::: "memory");
  __builtin_amdgcn_s_barrier();
  asm volatile("" ::: "memory");
  computeH(15);

  const float inv_h = 1.0f / 16.0f;
  const int lrow0 = l0 + w * 16;
#pragma unroll
  for (int ni = 0; ni < 4; ni++) {
#pragma unroll
    for (int r = 0; r < 4; r++) {
      int l = lrow0 + quad * 4 + r;
      int s = s0 + ni * 16 + l16;
      size_t idx = ((size_t)nb * 1024 + l) * 1024 + s;
      attn_out[idx] = accA[ni][r] * inv_h;
      sig_out[idx] = accS[ni][r] * inv_h;
    }
  }
}

// ---------------- K5: output projection v2 (same pipeline as qkv v2) ----------------
__global__ __launch_bounds__(256) void out_gemm(
    const unsigned short* __restrict__ o_h, const unsigned short* __restrict__ Wb,
    const float* __restrict__ bias, float* __restrict__ out) {
  __shared__ __align__(16) unsigned short As[5][4096];
  __shared__ __align__(16) unsigned short Bs[5][4096];
  const int tid = threadIdx.x;
  // XCD swizzle: 256 blocks = 8 XCDs x 32 (each XCD keeps one B-panel hot)
  const int flat = blockIdx.x + (blockIdx.y << 5);
  const int nf = (flat & 7) * 32 + (flat >> 3);
  const int bm = nf & 31, bn = nf >> 5;
  const unsigned short* Ag = o_h + (size_t)bm * 128 * 1024;
  const unsigned short* Bg = Wb + (size_t)bn * 128 * 1024;

  const int w = tid >> 6, lane = tid & 63;
  const int wm = w & 1, wn = w >> 1;
  const int quad = lane >> 4, l16 = lane & 15;

  f32x4 acc[4][4];
#pragma unroll
  for (int i = 0; i < 4; i++)
#pragma unroll
    for (int j = 0; j < 4; j++) { f32x4 zz = {0.f, 0.f, 0.f, 0.f}; acc[i][j] = zz; }

#pragma unroll
  for (int t = 0; t < 3; t++) {
    stage_tile(Ag + t * 32, As[t], tid);
    stage_tile(Bg + t * 32, Bs[t], tid);
  }

  int cb = 0, sb = 3;
#pragma unroll 1
  for (int kk = 0; kk < 32; kk++) {
    if (kk < 29) {
      stage_tile(Ag + (kk + 3) * 32, As[sb], tid);
      stage_tile(Bg + (kk + 3) * 32, Bs[sb], tid);
      sb = (sb == 4) ? 0 : sb + 1;
      asm volatile("s_waitcnt vmcnt(12)" ::: "memory");
    } else if (kk == 29) {
      asm volatile("s_waitcnt vmcnt(8)" ::: "memory");
    } else if (kk == 30) {
      asm volatile("s_waitcnt vmcnt(4)" ::: "memory");
    } else {
      asm volatile("s_waitcnt vmcnt(0)" ::: "memory");
    }
    __builtin_amdgcn_s_barrier();
    asm volatile("" ::: "memory");
    u16x8 af[4], bfv[4];
#pragma unroll
    for (int mi = 0; mi < 4; mi++) {
      int r = wm * 64 + mi * 16 + l16;
      af[mi] = *(const u16x8*)&As[cb][frag_off(r, quad)];
    }
#pragma unroll
    for (int ni = 0; ni < 4; ni++) {
      int r = wn * 64 + ni * 16 + l16;
      bfv[ni] = *(const u16x8*)&Bs[cb][frag_off(r, quad)];
    }
#pragma unroll
    for (int mi = 0; mi < 4; mi++)
#pragma unroll
      for (int ni = 0; ni < 4; ni++)
        acc[mi][ni] = mfma16(af[mi], bfv[ni], acc[mi][ni]);
    cb = (cb == 4) ? 0 : cb + 1;
  }
#pragma unroll
  for (int ni = 0; ni < 4; ni++) {
    int col = bn * 128 + wn * 64 + ni * 16 + l16;
    float bv = bias[col];
#pragma unroll
    for (int mi = 0; mi < 4; mi++) {
#pragma unroll
      for (int r = 0; r < 4; r++) {
        int t = bm * 128 + wm * 64 + mi * 16 + quad * 4 + r;
        out[(size_t)t * E_DIM + col] = acc[mi][ni][r] + bv;
      }
    }
  }
}

extern "C" void kernel_launch(void* const* d_in, const int* in_sizes, int n_in,
                              void* d_out, int out_size, void* d_ws, size_t ws_size,
                              hipStream_t stream) {
  const float* qin  = (const float*)d_in[0];
  const float* kin  = (const float*)d_in[1];
  const float* vin  = (const float*)d_in[2];
  const float* Wqkv = (const float*)d_in[3];
  const float* bqkv = (const float*)d_in[4];
  const float* Wout = (const float*)d_in[5];
  const float* bout = (const float*)d_in[6];
  float* out      = (float*)d_out;
  float* attn_out = out + 4194304;
  float* sig_out  = out + 8388608;

  unsigned short* q_hm = (unsigned short*)d_ws;      // [64][1024][64] bf16
  unsigned short* k_hm = q_hm + 4194304;             // [64][1024][64]
  unsigned short* v_t  = q_hm + 8388608;             // [64][64][1024]
  unsigned short* o_h  = q_hm + 12582912;            // [4096][1024]
  float* m_ws = (float*)(q_hm + 16777216);           // [64*1024]
  float* r_ws = m_ws + 65536;                        // [64*1024]

  unsigned short* qb = (unsigned short*)(out + 4194304);  // alias: attn/sig region
  unsigned short* kb = qb + 4194304;
  unsigned short* vb = qb + 8388608;
  unsigned short* Wqkvb = o_h;                            // alias: o_h region
  unsigned short* Woutb = v_t;                            // alias: v_t region (cast after attn)

  cast_kernel<<<dim3(2048, 4), 256, 0, stream>>>(
      qin, kin, vin, Wqkv, qb, kb, vb, Wqkvb,
      4194304, 4194304, 4194304, 3145728);
  qkv_gemm<<<dim3(32, 8, 3), 256, 0, stream>>>(qb, kb, vb, Wqkvb, bqkv,
                                               q_hm, k_hm, v_t);
  attn_kernel<<<dim3(32, 64), 256, 0, stream>>>(q_hm, k_hm, v_t, o_h, m_ws, r_ws);
  cast_kernel<<<dim3(512, 1), 256, 0, stream>>>(
      Wout, Wout, Wout, Wout, Woutb, Woutb, Woutb, Woutb,
      1048576, 0, 0, 0);
  weights_kernel<<<dim3(16, 16, 4), 256, 0, stream>>>(q_hm, k_hm, m_ws, r_ws,
                                                      attn_out, sig_out);
  out_gemm<<<dim3(32, 8), 256, 0, stream>>>(o_h, Woutb, bout, out);
}

// Round 5
// 250.204 us; speedup vs baseline: 1.0646x; 1.0646x over previous
//
#include <hip/hip_runtime.h>

// dims
#define L_DIM 1024
#define E_DIM 1024
#define NB 4
#define H_NUM 16
#define HD_DIM 64
#define T_TOK 4096   // L*NB
#define NHB 64       // NB*H_NUM

typedef float f32x4 __attribute__((ext_vector_type(4)));
typedef unsigned short u16x8 __attribute__((ext_vector_type(8)));
typedef unsigned short u16x4 __attribute__((ext_vector_type(4)));
typedef __bf16 bf16x8 __attribute__((ext_vector_type(8)));

__device__ inline unsigned short f2bf(float f) {
  unsigned int u = __builtin_bit_cast(unsigned int, f);
  u += 0x7FFFu + ((u >> 16) & 1u);
  return (unsigned short)(u >> 16);
}
__device__ inline f32x4 mfma16(u16x8 a, u16x8 b, f32x4 c) {
  return __builtin_amdgcn_mfma_f32_16x16x32_bf16(
      __builtin_bit_cast(bf16x8, a), __builtin_bit_cast(bf16x8, b), c, 0, 0, 0);
}

// async global->LDS 16B copy
__device__ __forceinline__ void gl2lds16(const void* g, void* l) {
  auto gp = reinterpret_cast<const __attribute__((address_space(1))) unsigned int*>(
      reinterpret_cast<unsigned long long>(g));
  auto lp = reinterpret_cast<__attribute__((address_space(3))) unsigned int*>(
      static_cast<unsigned int>(reinterpret_cast<unsigned long long>(l)));
  __builtin_amdgcn_global_load_lds(gp, lp, 16, 0, 0);
}

// ---------------- K0: f32 -> bf16 cast (up to 4 arrays per launch) ----------------
__global__ __launch_bounds__(256) void cast_kernel(
    const float* __restrict__ s0, const float* __restrict__ s1,
    const float* __restrict__ s2, const float* __restrict__ s3,
    unsigned short* __restrict__ d0, unsigned short* __restrict__ d1,
    unsigned short* __restrict__ d2, unsigned short* __restrict__ d3,
    int n0, int n1, int n2, int n3) {
  const int y = blockIdx.y;
  const float* s = (y == 0) ? s0 : (y == 1) ? s1 : (y == 2) ? s2 : s3;
  unsigned short* d = (y == 0) ? d0 : (y == 1) ? d1 : (y == 2) ? d2 : d3;
  const int n = (y == 0) ? n0 : (y == 1) ? n1 : (y == 2) ? n2 : n3;
  int idx = (blockIdx.x * 256 + threadIdx.x) * 8;
  const int stride = gridDim.x * 256 * 8;
  for (; idx < n; idx += stride) {
    float4 a = *(const float4*)(s + idx);
    float4 b = *(const float4*)(s + idx + 4);
    u16x8 o = {f2bf(a.x), f2bf(a.y), f2bf(a.z), f2bf(a.w),
               f2bf(b.x), f2bf(b.y), f2bf(b.z), f2bf(b.w)};
    *(u16x8*)(d + idx) = o;
  }
}

// ---- shared GEMM staging: 128 rows x 32 k bf16 tile (8 KB), swizzled ----
__device__ __forceinline__ void stage_tile(const unsigned short* __restrict__ g,
                                           unsigned short* lbuf, int tid) {
  const int r = tid >> 2, c = tid & 3;
  const int sc = c ^ ((r ^ (r >> 2)) & 3);
  gl2lds16(g + (size_t)r * 1024 + sc * 8, lbuf + tid * 8);
  const int r2 = r + 64;
  gl2lds16(g + (size_t)r2 * 1024 + sc * 8, lbuf + (tid + 256) * 8);
}
__device__ __forceinline__ int frag_off(int r, int q) {
  return r * 32 + ((q ^ ((r ^ (r >> 2)) & 3)) << 3);
}

// ---------------- K1: packed QKV projection v3 ----------------
// m97 structure + 3-buffer ring, depth-1 across barrier (vmcnt(4)).
// LDS 48 KB -> 3 blocks/CU preserved. Original grid mapping (no swizzle).
__global__ __launch_bounds__(256) void qkv_gemm(
    const unsigned short* __restrict__ qb, const unsigned short* __restrict__ kb,
    const unsigned short* __restrict__ vb, const unsigned short* __restrict__ Wb,
    const float* __restrict__ bias, unsigned short* __restrict__ q_hm,
    unsigned short* __restrict__ k_hm, unsigned short* __restrict__ v_t) {
  __shared__ __align__(16) unsigned short As[3][4096];   // 24 KB
  __shared__ __align__(16) unsigned short Bs[3][4096];   // 24 KB
  const int tid = threadIdx.x;
  const int bm = blockIdx.x, bn = blockIdx.y, z = blockIdx.z;
  const unsigned short* Ag = ((z == 0) ? qb : (z == 1) ? kb : vb) + (size_t)bm * 128 * 1024;
  const unsigned short* Bg = Wb + (size_t)z * 1048576 + (size_t)bn * 128 * 1024;
  const float* bc = bias + z * E_DIM;

  const int w = tid >> 6, lane = tid & 63;
  const int wm = w & 1, wn = w >> 1;
  const int quad = lane >> 4, l16 = lane & 15;

  f32x4 acc[4][4];
#pragma unroll
  for (int i = 0; i < 4; i++)
#pragma unroll
    for (int j = 0; j < 4; j++) { f32x4 zz = {0.f, 0.f, 0.f, 0.f}; acc[i][j] = zz; }

  stage_tile(Ag, As[0], tid);
  stage_tile(Bg, Bs[0], tid);

  int cb = 0, sb = 1;
#pragma unroll 1
  for (int kk = 0; kk < 32; kk++) {
    if (kk + 1 < 32) {
      stage_tile(Ag + (kk + 1) * 32, As[sb], tid);
      stage_tile(Bg + (kk + 1) * 32, Bs[sb], tid);
      sb = (sb == 2) ? 0 : sb + 1;
      asm volatile("s_waitcnt vmcnt(4)" ::: "memory");   // tile kk landed; kk+1 in flight
    } else {
      asm volatile("s_waitcnt vmcnt(0)" ::: "memory");
    }
    __builtin_amdgcn_s_barrier();
    asm volatile("" ::: "memory");
    u16x8 af[4], bfv[4];
#pragma unroll
    for (int mi = 0; mi < 4; mi++) {
      int r = wm * 64 + mi * 16 + l16;
      af[mi] = *(const u16x8*)&As[cb][frag_off(r, quad)];
    }
#pragma unroll
    for (int ni = 0; ni < 4; ni++) {
      int r = wn * 64 + ni * 16 + l16;
      bfv[ni] = *(const u16x8*)&Bs[cb][frag_off(r, quad)];
    }
#pragma unroll
    for (int mi = 0; mi < 4; mi++)
#pragma unroll
      for (int ni = 0; ni < 4; ni++)
        acc[mi][ni] = mfma16(af[mi], bfv[ni], acc[mi][ni]);
    cb = (cb == 2) ? 0 : cb + 1;
  }
#pragma unroll
  for (int ni = 0; ni < 4; ni++) {
    int col = bn * 128 + wn * 64 + ni * 16 + l16;
    float bv = bc[col];
    int h = col >> 6, d = col & 63;
#pragma unroll
    for (int mi = 0; mi < 4; mi++) {
#pragma unroll
      for (int r = 0; r < 4; r++) {
        int t = bm * 128 + wm * 64 + mi * 16 + quad * 4 + r;
        float v = acc[mi][ni][r] + bv;
        int nb = t & 3, pos = t >> 2;
        if (z == 0) {
          v *= 0.125f;
          q_hm[(size_t)((nb * 16 + h) * 1024 + pos) * 64 + d] = f2bf(v);
        } else if (z == 1) {
          k_hm[(size_t)((nb * 16 + h) * 1024 + pos) * 64 + d] = f2bf(v);
        } else {
          v_t[(size_t)((nb * 16 + h) * 64 + d) * 1024 + pos] = f2bf(v);
        }
      }
    }
  }
}

// ---------------- K3: attention core v4 (round-2 winner, unchanged) ----------------
__global__ __launch_bounds__(256, 2) void attn_kernel(
    const unsigned short* __restrict__ q_hm, const unsigned short* __restrict__ k_hm,
    const unsigned short* __restrict__ v_t, unsigned short* __restrict__ o_h,
    float* __restrict__ m_ws, float* __restrict__ r_ws) {
  __shared__ __align__(16) unsigned short stage[8][4096];   // 8 x 64x64 bf16 tiles
  __shared__ __align__(16) unsigned short pt[2][32][68];    // rotating P tile (l x s_local)
  __shared__ float red_m[4][32];
  __shared__ float red_s[4][32];

  const int tid = threadIdx.x;
  // XCD-bijective swizzle: linear id -> (xcd, local) -> contiguous heads per XCD
  const int flat = blockIdx.x + (blockIdx.y << 5);   // 0..2047
  const int nf = (flat & 7) * 256 + (flat >> 3);
  const int l0 = (nf & 31) * 32;
  const int b = nf >> 5;
  const int nb = b >> 4, h = b & 15;
  const int w = tid >> 6, lane = tid & 63;
  const int quad = lane >> 4, l16 = lane & 15;

  const int i1 = tid + 256;
  const int r0s = tid >> 3, c0s = tid & 7;
  const int r1s = i1 >> 3, c1s = i1 & 7;
  const int src0 = (c0s ^ (r0s & 7)) * 8;
  const int src1 = (c1s ^ (r1s & 7)) * 8;

  const unsigned short* kbase = k_hm + ((size_t)b << 16);
  const unsigned short* vbase = v_t + ((size_t)b << 16);

  // Q fragments for the 2 l-groups (B-operand, n = l) -- issue BEFORE staging
  u16x8 bq[2][2];
#pragma unroll
  for (int g = 0; g < 2; g++) {
    const unsigned short* qp =
        q_hm + ((size_t)(b * 1024 + l0 + g * 16 + l16) << 6) + quad * 8;
    bq[g][0] = *(const u16x8*)qp;
    bq[g][1] = *(const u16x8*)(qp + 32);
  }
  asm volatile("" ::: "memory");   // pin bq loads before the staging stream

  f32x4 acc[16][2];
#pragma unroll
  for (int j = 0; j < 16; j++)
#pragma unroll
    for (int g = 0; g < 2; g++) { f32x4 z = {0.f, 0.f, 0.f, 0.f}; acc[j][g] = z; }

  // prologue: stage K0..K2 (depth 3)
#pragma unroll
  for (int t = 0; t < 3; t++) {
    gl2lds16(kbase + ((size_t)(t * 64 + r0s) << 6) + src0, &stage[t][tid * 8]);
    gl2lds16(kbase + ((size_t)(t * 64 + r1s) << 6) + src1, &stage[t][i1 * 8]);
  }

  const int myrow = w * 16 + l16;
  const int sw0 = ((quad ^ (l16 & 7)) * 8);
  const int sw1 = (((quad + 4) ^ (l16 & 7)) * 8);

  // ---- phase 1: scores ----
#pragma unroll
  for (int j = 0; j < 16; j++) {
    if (j + 3 < 16) {
      gl2lds16(kbase + ((size_t)((j + 3) * 64 + r0s) << 6) + src0,
               &stage[(j + 3) & 7][tid * 8]);
      gl2lds16(kbase + ((size_t)((j + 3) * 64 + r1s) << 6) + src1,
               &stage[(j + 3) & 7][i1 * 8]);
    } else {
      // pipeline handoff: stage V tiles 0..2 for phase 3
      const int vt = j + 3 - 16;
      gl2lds16(vbase + ((size_t)r0s << 10) + vt * 64 + src0,
               &stage[(j + 3) & 7][tid * 8]);
      gl2lds16(vbase + ((size_t)r1s << 10) + vt * 64 + src1,
               &stage[(j + 3) & 7][i1 * 8]);
    }
    asm volatile("s_waitcnt vmcnt(6)" ::: "memory");  // tile j landed; 3 in flight
    __builtin_amdgcn_s_barrier();
    asm volatile("" ::: "memory");
    const unsigned short* kt = &stage[j & 7][myrow * 64];
    u16x8 ak0 = *(const u16x8*)(kt + sw0);
    u16x8 ak1 = *(const u16x8*)(kt + sw1);
    acc[j][0] = mfma16(ak0, bq[0][0], acc[j][0]);
    acc[j][0] = mfma16(ak1, bq[0][1], acc[j][0]);
    acc[j][1] = mfma16(ak0, bq[1][0], acc[j][1]);
    acc[j][1] = mfma16(ak1, bq[1][1], acc[j][1]);
  }

  // ---- phase 2: softmax stats (barriers wait lgkmcnt only; V0..V2 in flight) ----
  float lm0 = -3e38f, lm1 = -3e38f;
#pragma unroll
  for (int j = 0; j < 16; j++)
#pragma unroll
    for (int r = 0; r < 4; r++) {
      lm0 = fmaxf(lm0, acc[j][0][r]);
      lm1 = fmaxf(lm1, acc[j][1][r]);
    }
  lm0 = fmaxf(lm0, __shfl_xor(lm0, 16, 64));
  lm0 = fmaxf(lm0, __shfl_xor(lm0, 32, 64));
  lm1 = fmaxf(lm1, __shfl_xor(lm1, 16, 64));
  lm1 = fmaxf(lm1, __shfl_xor(lm1, 32, 64));
  if (lane < 16) { red_m[w][lane] = lm0; red_m[w][lane + 16] = lm1; }
  asm volatile("s_waitcnt lgkmcnt(0)" ::: "memory");
  __builtin_amdgcn_s_barrier();
  asm volatile("" ::: "memory");
  float m0 = fmaxf(fmaxf(red_m[0][l16], red_m[1][l16]),
                   fmaxf(red_m[2][l16], red_m[3][l16]));
  float m1 = fmaxf(fmaxf(red_m[0][l16 + 16], red_m[1][l16 + 16]),
                   fmaxf(red_m[2][l16 + 16], red_m[3][l16 + 16]));
  float mm = 0.f;
  if (tid < 32)
    mm = fmaxf(fmaxf(red_m[0][tid], red_m[1][tid]),
               fmaxf(red_m[2][tid], red_m[3][tid]));

  float ls0 = 0.f, ls1 = 0.f;
#pragma unroll
  for (int j = 0; j < 16; j++) {
#pragma unroll
    for (int r = 0; r < 4; r++) {
      float e0 = __expf(acc[j][0][r] - m0);
      float e1 = __expf(acc[j][1][r] - m1);
      acc[j][0][r] = e0;
      acc[j][1][r] = e1;
      ls0 += e0;
      ls1 += e1;
    }
  }
  ls0 += __shfl_xor(ls0, 16, 64);
  ls0 += __shfl_xor(ls0, 32, 64);
  ls1 += __shfl_xor(ls1, 16, 64);
  ls1 += __shfl_xor(ls1, 32, 64);
  if (lane < 16) { red_s[w][lane] = ls0; red_s[w][lane + 16] = ls1; }
  asm volatile("s_waitcnt lgkmcnt(0)" ::: "memory");
  __builtin_amdgcn_s_barrier();
  asm volatile("" ::: "memory");
  float rv0 = 1.0f / (red_s[0][l16] + red_s[1][l16] + red_s[2][l16] + red_s[3][l16]);
  float rv1 = 1.0f / (red_s[0][l16 + 16] + red_s[1][l16 + 16] +
                      red_s[2][l16 + 16] + red_s[3][l16 + 16]);
  float ssv = 1.f;
  if (tid < 32)
    ssv = red_s[0][tid] + red_s[1][tid] + red_s[2][tid] + red_s[3][tid];

  // ---- phase 3: PV with rotating P-tile transpose, depth-3 V pipeline ----
  {
    u16x4 p0 = {f2bf(acc[0][0][0]), f2bf(acc[0][0][1]), f2bf(acc[0][0][2]), f2bf(acc[0][0][3])};
    u16x4 p1 = {f2bf(acc[0][1][0]), f2bf(acc[0][1][1]), f2bf(acc[0][1][2]), f2bf(acc[0][1][3])};
    *(u16x4*)&pt[0][l16][w * 16 + quad * 4] = p0;
    *(u16x4*)&pt[0][16 + l16][w * 16 + quad * 4] = p1;
  }

  f32x4 oacc0 = {0.f, 0.f, 0.f, 0.f};
  f32x4 oacc1 = {0.f, 0.f, 0.f, 0.f};
#pragma unroll
  for (int j = 0; j < 16; j++) {
    if (j < 13) {
      const int t = j + 3;
      gl2lds16(vbase + ((size_t)r0s << 10) + t * 64 + src0, &stage[t & 7][tid * 8]);
      gl2lds16(vbase + ((size_t)r1s << 10) + t * 64 + src1, &stage[t & 7][i1 * 8]);
      asm volatile("s_waitcnt vmcnt(6) lgkmcnt(0)" ::: "memory");
    } else if (j == 13) {
      asm volatile("s_waitcnt vmcnt(4) lgkmcnt(0)" ::: "memory");
    } else if (j == 14) {
      asm volatile("s_waitcnt vmcnt(2) lgkmcnt(0)" ::: "memory");
    } else {
      asm volatile("s_waitcnt vmcnt(0) lgkmcnt(0)" ::: "memory");
    }
    __builtin_amdgcn_s_barrier();
    asm volatile("" ::: "memory");
    if (j < 15) {
      const int bf = (j + 1) & 1;
      u16x4 p0 = {f2bf(acc[j + 1][0][0]), f2bf(acc[j + 1][0][1]),
                  f2bf(acc[j + 1][0][2]), f2bf(acc[j + 1][0][3])};
      u16x4 p1 = {f2bf(acc[j + 1][1][0]), f2bf(acc[j + 1][1][1]),
                  f2bf(acc[j + 1][1][2]), f2bf(acc[j + 1][1][3])};
      *(u16x4*)&pt[bf][l16][w * 16 + quad * 4] = p0;
      *(u16x4*)&pt[bf][16 + l16][w * 16 + quad * 4] = p1;
    }
    const unsigned short* vt = &stage[j & 7][myrow * 64];
    u16x8 bv0 = *(const u16x8*)(vt + sw0);
    u16x8 bv1 = *(const u16x8*)(vt + sw1);
    u16x8 ap00 = *(const u16x8*)&pt[j & 1][l16][quad * 8];
    u16x8 ap01 = *(const u16x8*)&pt[j & 1][l16][32 + quad * 8];
    u16x8 ap10 = *(const u16x8*)&pt[j & 1][16 + l16][quad * 8];
    u16x8 ap11 = *(const u16x8*)&pt[j & 1][16 + l16][32 + quad * 8];
    oacc0 = mfma16(ap00, bv0, oacc0);
    oacc0 = mfma16(ap01, bv1, oacc0);
    oacc1 = mfma16(ap10, bv0, oacc1);
    oacc1 = mfma16(ap11, bv1, oacc1);
  }

  if (tid < 32) {
    m_ws[b * 1024 + l0 + tid] = mm;
    r_ws[b * 1024 + l0 + tid] = 1.0f / ssv;
  }

#pragma unroll
  for (int r = 0; r < 4; r++) {
    int lr = quad * 4 + r;
    float rr0 = __shfl(rv0, lr, 64);
    float rr1 = __shfl(rv1, lr, 64);
    int t0 = (l0 + lr) * 4 + nb;
    int t1 = (l0 + 16 + lr) * 4 + nb;
    o_h[((size_t)t0 << 10) + h * 64 + w * 16 + l16] = f2bf(oacc0[r] * rr0);
    o_h[((size_t)t1 << 10) + h * 64 + w * 16 + l16] = f2bf(oacc1[r] * rr1);
  }
}

// ---------------- K4: head-averaged attn + sigmoid weights v2 (unchanged) ----------------
__global__ __launch_bounds__(256, 2) void weights_kernel(
    const unsigned short* __restrict__ q_hm, const unsigned short* __restrict__ k_hm,
    const float* __restrict__ m_ws, const float* __restrict__ r_ws,
    float* __restrict__ attn_out, float* __restrict__ sig_out) {
  __shared__ __align__(16) unsigned short qs[4][4096];   // 32 KB
  __shared__ __align__(16) unsigned short ks[4][4096];   // 32 KB
  __shared__ float ml[16][64];
  __shared__ float rl[16][64];
  __shared__ float cl[16][64];

  const int tid = threadIdx.x;
  const int flat = blockIdx.x + (blockIdx.y << 4) + (blockIdx.z << 8);
  const int xcd = flat & 7, local = flat >> 3;           // local: 0..127
  const int nb = xcd >> 1;
  const int idx2 = ((xcd & 1) << 7) + local;             // 0..255
  const int l0 = (idx2 >> 4) << 6;
  const int s0 = (idx2 & 15) << 6;

  const int w = tid >> 6, lane = tid & 63;
  const int quad = lane >> 4, l16 = lane & 15;

  const int i1 = tid + 256;
  const int r0s = tid >> 3, c0s = tid & 7;
  const int r1s = i1 >> 3, c1s = i1 & 7;
  const int src0 = (c0s ^ (r0s & 7)) * 8;
  const int src1 = (c1s ^ (r1s & 7)) * 8;

  {
    int idx = tid * 4;
    int hh = idx >> 6, ii = idx & 63;
    int bb = nb * 16 + hh;
    float4 mv4 = *(const float4*)&m_ws[bb * 1024 + l0 + ii];
    float4 rv4 = *(const float4*)&r_ws[bb * 1024 + l0 + ii];
    *(float4*)&ml[hh][ii] = mv4;
    *(float4*)&rl[hh][ii] = rv4;
    float4 cv4 = {__expf(-mv4.x), __expf(-mv4.y), __expf(-mv4.z), __expf(-mv4.w)};
    *(float4*)&cl[hh][ii] = cv4;
  }

  const int sw0 = ((quad ^ (l16 & 7)) * 8);
  const int sw1 = (((quad + 4) ^ (l16 & 7)) * 8);

  auto stageQK = [&](int h) {
    const int bb = nb * 16 + h;
    const unsigned short* qb = q_hm + ((size_t)(bb * 1024 + l0) << 6);
    const unsigned short* kb = k_hm + ((size_t)(bb * 1024 + s0) << 6);
    const int bf = h & 3;
    gl2lds16(qb + (r0s << 6) + src0, &qs[bf][tid * 8]);
    gl2lds16(qb + (r1s << 6) + src1, &qs[bf][i1 * 8]);
    gl2lds16(kb + (r0s << 6) + src0, &ks[bf][tid * 8]);
    gl2lds16(kb + (r1s << 6) + src1, &ks[bf][i1 * 8]);
  };

  f32x4 accA[4], accS[4];
#pragma unroll
  for (int i = 0; i < 4; i++) {
    f32x4 zz = {0.f, 0.f, 0.f, 0.f};
    accA[i] = zz; accS[i] = zz;
  }

  stageQK(0);
  stageQK(1);
  asm volatile("s_waitcnt lgkmcnt(0)" ::: "memory");  // ml/rl/cl ds_writes done

  auto computeH = [&](int h) {
    const int bf = h & 3;
    const unsigned short* qt = &qs[bf][(w * 16 + l16) * 64];
    u16x8 a0 = *(const u16x8*)(qt + sw0);
    u16x8 a1 = *(const u16x8*)(qt + sw1);
    f32x4 mv = *(const f32x4*)&ml[h][w * 16 + quad * 4];
    f32x4 rv = *(const f32x4*)&rl[h][w * 16 + quad * 4];
    f32x4 cv = *(const f32x4*)&cl[h][w * 16 + quad * 4];
#pragma unroll
    for (int ni = 0; ni < 4; ni++) {
      const unsigned short* kt = &ks[bf][(ni * 16 + l16) * 64];
      u16x8 b0 = *(const u16x8*)(kt + sw0);
      u16x8 b1 = *(const u16x8*)(kt + sw1);
      f32x4 scv = {0.f, 0.f, 0.f, 0.f};
      scv = mfma16(a0, b0, scv);
      scv = mfma16(a1, b1, scv);
#pragma unroll
      for (int r = 0; r < 4; r++) {
        float e = __expf(scv[r] - mv[r]);
        accA[ni][r] += e * rv[r];
        accS[ni][r] += e * __builtin_amdgcn_rcpf(e + cv[r]);
      }
    }
  };

#pragma unroll 1
  for (int h = 0; h < 14; ++h) {
    stageQK(h + 2);
    asm volatile("s_waitcnt vmcnt(8)" ::: "memory");
    __builtin_amdgcn_s_barrier();
    asm volatile("" ::: "memory");
    computeH(h);
  }
  asm volatile("s_waitcnt vmcnt(4)" ::: "memory");
  __builtin_amdgcn_s_barrier();
  asm volatile("" ::: "memory");
  computeH(14);
  asm volatile("s_waitcnt vmcnt(0)" ::: "memory");
  __builtin_amdgcn_s_barrier();
  asm volatile("" ::: "memory");
  computeH(15);

  const float inv_h = 1.0f / 16.0f;
  const int lrow0 = l0 + w * 16;
#pragma unroll
  for (int ni = 0; ni < 4; ni++) {
#pragma unroll
    for (int r = 0; r < 4; r++) {
      int l = lrow0 + quad * 4 + r;
      int s = s0 + ni * 16 + l16;
      size_t idx = ((size_t)nb * 1024 + l) * 1024 + s;
      attn_out[idx] = accA[ni][r] * inv_h;
      sig_out[idx] = accS[ni][r] * inv_h;
    }
  }
}

// ---------------- K5: output projection v3 (3-buffer ring, vmcnt(4)) ----------------
__global__ __launch_bounds__(256) void out_gemm(
    const unsigned short* __restrict__ o_h, const unsigned short* __restrict__ Wb,
    const float* __restrict__ bias, float* __restrict__ out) {
  __shared__ __align__(16) unsigned short As[3][4096];
  __shared__ __align__(16) unsigned short Bs[3][4096];
  const int tid = threadIdx.x;
  const int bm = blockIdx.x, bn = blockIdx.y;
  const unsigned short* Ag = o_h + (size_t)bm * 128 * 1024;
  const unsigned short* Bg = Wb + (size_t)bn * 128 * 1024;

  const int w = tid >> 6, lane = tid & 63;
  const int wm = w & 1, wn = w >> 1;
  const int quad = lane >> 4, l16 = lane & 15;

  f32x4 acc[4][4];
#pragma unroll
  for (int i = 0; i < 4; i++)
#pragma unroll
    for (int j = 0; j < 4; j++) { f32x4 zz = {0.f, 0.f, 0.f, 0.f}; acc[i][j] = zz; }

  stage_tile(Ag, As[0], tid);
  stage_tile(Bg, Bs[0], tid);

  int cb = 0, sb = 1;
#pragma unroll 1
  for (int kk = 0; kk < 32; kk++) {
    if (kk + 1 < 32) {
      stage_tile(Ag + (kk + 1) * 32, As[sb], tid);
      stage_tile(Bg + (kk + 1) * 32, Bs[sb], tid);
      sb = (sb == 2) ? 0 : sb + 1;
      asm volatile("s_waitcnt vmcnt(4)" ::: "memory");
    } else {
      asm volatile("s_waitcnt vmcnt(0)" ::: "memory");
    }
    __builtin_amdgcn_s_barrier();
    asm volatile("" ::: "memory");
    u16x8 af[4], bfv[4];
#pragma unroll
    for (int mi = 0; mi < 4; mi++) {
      int r = wm * 64 + mi * 16 + l16;
      af[mi] = *(const u16x8*)&As[cb][frag_off(r, quad)];
    }
#pragma unroll
    for (int ni = 0; ni < 4; ni++) {
      int r = wn * 64 + ni * 16 + l16;
      bfv[ni] = *(const u16x8*)&Bs[cb][frag_off(r, quad)];
    }
#pragma unroll
    for (int mi = 0; mi < 4; mi++)
#pragma unroll
      for (int ni = 0; ni < 4; ni++)
        acc[mi][ni] = mfma16(af[mi], bfv[ni], acc[mi][ni]);
    cb = (cb == 2) ? 0 : cb + 1;
  }
#pragma unroll
  for (int ni = 0; ni < 4; ni++) {
    int col = bn * 128 + wn * 64 + ni * 16 + l16;
    float bv = bias[col];
#pragma unroll
    for (int mi = 0; mi < 4; mi++) {
#pragma unroll
      for (int r = 0; r < 4; r++) {
        int t = bm * 128 + wm * 64 + mi * 16 + quad * 4 + r;
        out[(size_t)t * E_DIM + col] = acc[mi][ni][r] + bv;
      }
    }
  }
}

extern "C" void kernel_launch(void* const* d_in, const int* in_sizes, int n_in,
                              void* d_out, int out_size, void* d_ws, size_t ws_size,
                              hipStream_t stream) {
  const float* qin  = (const float*)d_in[0];
  const float* kin  = (const float*)d_in[1];
  const float* vin  = (const float*)d_in[2];
  const float* Wqkv = (const float*)d_in[3];
  const float* bqkv = (const float*)d_in[4];
  const float* Wout = (const float*)d_in[5];
  const float* bout = (const float*)d_in[6];
  float* out      = (float*)d_out;
  float* attn_out = out + 4194304;
  float* sig_out  = out + 8388608;

  unsigned short* q_hm = (unsigned short*)d_ws;      // [64][1024][64] bf16
  unsigned short* k_hm = q_hm + 4194304;             // [64][1024][64]
  unsigned short* v_t  = q_hm + 8388608;             // [64][64][1024]
  unsigned short* o_h  = q_hm + 12582912;            // [4096][1024]
  float* m_ws = (float*)(q_hm + 16777216);           // [64*1024]
  float* r_ws = m_ws + 65536;                        // [64*1024]

  unsigned short* qb = (unsigned short*)(out + 4194304);  // alias: attn/sig region
  unsigned short* kb = qb + 4194304;
  unsigned short* vb = qb + 8388608;
  unsigned short* Wqkvb = o_h;                            // alias: o_h region
  unsigned short* Woutb = v_t;                            // alias: v_t region (cast after attn)

  cast_kernel<<<dim3(2048, 4), 256, 0, stream>>>(
      qin, kin, vin, Wqkv, qb, kb, vb, Wqkvb,
      4194304, 4194304, 4194304, 3145728);
  qkv_gemm<<<dim3(32, 8, 3), 256, 0, stream>>>(qb, kb, vb, Wqkvb, bqkv,
                                               q_hm, k_hm, v_t);
  attn_kernel<<<dim3(32, 64), 256, 0, stream>>>(q_hm, k_hm, v_t, o_h, m_ws, r_ws);
  cast_kernel<<<dim3(512, 1), 256, 0, stream>>>(
      Wout, Wout, Wout, Wout, Woutb, Woutb, Woutb, Woutb,
      1048576, 0, 0, 0);
  weights_kernel<<<dim3(16, 16, 4), 256, 0, stream>>>(q_hm, k_hm, m_ws, r_ws,
                                                      attn_out, sig_out);
  out_gemm<<<dim3(32, 8), 256, 0, stream>>>(o_h, Woutb, bout, out);
}

// Round 6
// 249.955 us; speedup vs baseline: 1.0657x; 1.0010x over previous
//
#include <hip/hip_runtime.h>

// dims
#define L_DIM 1024
#define E_DIM 1024
#define NB 4
#define H_NUM 16
#define HD_DIM 64
#define T_TOK 4096   // L*NB
#define NHB 64       // NB*H_NUM

typedef float f32x4 __attribute__((ext_vector_type(4)));
typedef unsigned short u16x8 __attribute__((ext_vector_type(8)));
typedef unsigned short u16x4 __attribute__((ext_vector_type(4)));
typedef __bf16 bf16x8 __attribute__((ext_vector_type(8)));

__device__ inline unsigned short f2bf(float f) {
  unsigned int u = __builtin_bit_cast(unsigned int, f);
  u += 0x7FFFu + ((u >> 16) & 1u);
  return (unsigned short)(u >> 16);
}
// packed f32x2 -> bf16x2 (RNE), single VALU instruction
__device__ __forceinline__ unsigned int cvt_pk_bf16(float lo, float hi) {
  unsigned int r;
  asm("v_cvt_pk_bf16_f32 %0, %1, %2" : "=v"(r) : "v"(lo), "v"(hi));
  return r;
}
__device__ inline f32x4 mfma16(u16x8 a, u16x8 b, f32x4 c) {
  return __builtin_amdgcn_mfma_f32_16x16x32_bf16(
      __builtin_bit_cast(bf16x8, a), __builtin_bit_cast(bf16x8, b), c, 0, 0, 0);
}

// async global->LDS 16B copy
__device__ __forceinline__ void gl2lds16(const void* g, void* l) {
  auto gp = reinterpret_cast<const __attribute__((address_space(1))) unsigned int*>(
      reinterpret_cast<unsigned long long>(g));
  auto lp = reinterpret_cast<__attribute__((address_space(3))) unsigned int*>(
      static_cast<unsigned int>(reinterpret_cast<unsigned long long>(l)));
  __builtin_amdgcn_global_load_lds(gp, lp, 16, 0, 0);
}

// ---------------- K0: f32 -> bf16 cast (up to 4 arrays per launch) ----------------
__global__ __launch_bounds__(256) void cast_kernel(
    const float* __restrict__ s0, const float* __restrict__ s1,
    const float* __restrict__ s2, const float* __restrict__ s3,
    unsigned short* __restrict__ d0, unsigned short* __restrict__ d1,
    unsigned short* __restrict__ d2, unsigned short* __restrict__ d3,
    int n0, int n1, int n2, int n3) {
  const int y = blockIdx.y;
  const float* s = (y == 0) ? s0 : (y == 1) ? s1 : (y == 2) ? s2 : s3;
  unsigned short* d = (y == 0) ? d0 : (y == 1) ? d1 : (y == 2) ? d2 : d3;
  const int n = (y == 0) ? n0 : (y == 1) ? n1 : (y == 2) ? n2 : n3;
  int idx = (blockIdx.x * 256 + threadIdx.x) * 8;
  const int stride = gridDim.x * 256 * 8;
  for (; idx < n; idx += stride) {
    float4 a = *(const float4*)(s + idx);
    float4 b = *(const float4*)(s + idx + 4);
    u16x8 o = {f2bf(a.x), f2bf(a.y), f2bf(a.z), f2bf(a.w),
               f2bf(b.x), f2bf(b.y), f2bf(b.z), f2bf(b.w)};
    *(u16x8*)(d + idx) = o;
  }
}

// ---- shared GEMM staging: 128 rows x 32 k bf16 tile (8 KB), swizzled ----
__device__ __forceinline__ void stage_tile(const unsigned short* __restrict__ g,
                                           unsigned short* lbuf, int tid) {
  const int r = tid >> 2, c = tid & 3;
  const int sc = c ^ ((r ^ (r >> 2)) & 3);
  gl2lds16(g + (size_t)r * 1024 + sc * 8, lbuf + tid * 8);
  const int r2 = r + 64;
  gl2lds16(g + (size_t)r2 * 1024 + sc * 8, lbuf + (tid + 256) * 8);
}
__device__ __forceinline__ int frag_off(int r, int q) {
  return r * 32 + ((q ^ ((r ^ (r >> 2)) & 3)) << 3);
}

// ---------------- K1: packed QKV projection v3 (round-5 winner, unchanged) ----------------
__global__ __launch_bounds__(256) void qkv_gemm(
    const unsigned short* __restrict__ qb, const unsigned short* __restrict__ kb,
    const unsigned short* __restrict__ vb, const unsigned short* __restrict__ Wb,
    const float* __restrict__ bias, unsigned short* __restrict__ q_hm,
    unsigned short* __restrict__ k_hm, unsigned short* __restrict__ v_t) {
  __shared__ __align__(16) unsigned short As[3][4096];   // 24 KB
  __shared__ __align__(16) unsigned short Bs[3][4096];   // 24 KB
  const int tid = threadIdx.x;
  const int bm = blockIdx.x, bn = blockIdx.y, z = blockIdx.z;
  const unsigned short* Ag = ((z == 0) ? qb : (z == 1) ? kb : vb) + (size_t)bm * 128 * 1024;
  const unsigned short* Bg = Wb + (size_t)z * 1048576 + (size_t)bn * 128 * 1024;
  const float* bc = bias + z * E_DIM;

  const int w = tid >> 6, lane = tid & 63;
  const int wm = w & 1, wn = w >> 1;
  const int quad = lane >> 4, l16 = lane & 15;

  f32x4 acc[4][4];
#pragma unroll
  for (int i = 0; i < 4; i++)
#pragma unroll
    for (int j = 0; j < 4; j++) { f32x4 zz = {0.f, 0.f, 0.f, 0.f}; acc[i][j] = zz; }

  stage_tile(Ag, As[0], tid);
  stage_tile(Bg, Bs[0], tid);

  int cb = 0, sb = 1;
#pragma unroll 1
  for (int kk = 0; kk < 32; kk++) {
    if (kk + 1 < 32) {
      stage_tile(Ag + (kk + 1) * 32, As[sb], tid);
      stage_tile(Bg + (kk + 1) * 32, Bs[sb], tid);
      sb = (sb == 2) ? 0 : sb + 1;
      asm volatile("s_waitcnt vmcnt(4)" ::: "memory");   // tile kk landed; kk+1 in flight
    } else {
      asm volatile("s_waitcnt vmcnt(0)" ::: "memory");
    }
    __builtin_amdgcn_s_barrier();
    asm volatile("" ::: "memory");
    u16x8 af[4], bfv[4];
#pragma unroll
    for (int mi = 0; mi < 4; mi++) {
      int r = wm * 64 + mi * 16 + l16;
      af[mi] = *(const u16x8*)&As[cb][frag_off(r, quad)];
    }
#pragma unroll
    for (int ni = 0; ni < 4; ni++) {
      int r = wn * 64 + ni * 16 + l16;
      bfv[ni] = *(const u16x8*)&Bs[cb][frag_off(r, quad)];
    }
#pragma unroll
    for (int mi = 0; mi < 4; mi++)
#pragma unroll
      for (int ni = 0; ni < 4; ni++)
        acc[mi][ni] = mfma16(af[mi], bfv[ni], acc[mi][ni]);
    cb = (cb == 2) ? 0 : cb + 1;
  }
#pragma unroll
  for (int ni = 0; ni < 4; ni++) {
    int col = bn * 128 + wn * 64 + ni * 16 + l16;
    float bv = bc[col];
    int h = col >> 6, d = col & 63;
#pragma unroll
    for (int mi = 0; mi < 4; mi++) {
#pragma unroll
      for (int r = 0; r < 4; r++) {
        int t = bm * 128 + wm * 64 + mi * 16 + quad * 4 + r;
        float v = acc[mi][ni][r] + bv;
        int nb = t & 3, pos = t >> 2;
        if (z == 0) {
          v *= 0.125f;
          q_hm[(size_t)((nb * 16 + h) * 1024 + pos) * 64 + d] = f2bf(v);
        } else if (z == 1) {
          k_hm[(size_t)((nb * 16 + h) * 1024 + pos) * 64 + d] = f2bf(v);
        } else {
          v_t[(size_t)((nb * 16 + h) * 64 + d) * 1024 + pos] = f2bf(v);
        }
      }
    }
  }
}

// ---------------- K3: attention core v6 ----------------
// v6 = round-2 v4 + depth-5 prefetch (same 8 buffers; stage j+5, vmcnt(10))
//      + v_cvt_pk_bf16_f32 for P-tile packing.
// Ring safety at depth-5/8buf: stage of tile j+5 (after barrier j-1) overwrites
// tile j-3, whose cross-wave reads finished before barrier j-2. Registers and
// LDS unchanged -> same 2 blocks/CU residency.
__global__ __launch_bounds__(256, 2) void attn_kernel(
    const unsigned short* __restrict__ q_hm, const unsigned short* __restrict__ k_hm,
    const unsigned short* __restrict__ v_t, unsigned short* __restrict__ o_h,
    float* __restrict__ m_ws, float* __restrict__ r_ws) {
  __shared__ __align__(16) unsigned short stage[8][4096];   // 8 x 64x64 bf16 tiles
  __shared__ __align__(16) unsigned short pt[2][32][68];    // rotating P tile (l x s_local)
  __shared__ float red_m[4][32];
  __shared__ float red_s[4][32];

  const int tid = threadIdx.x;
  // XCD-bijective swizzle: linear id -> (xcd, local) -> contiguous heads per XCD
  const int flat = blockIdx.x + (blockIdx.y << 5);   // 0..2047
  const int nf = (flat & 7) * 256 + (flat >> 3);
  const int l0 = (nf & 31) * 32;
  const int b = nf >> 5;
  const int nb = b >> 4, h = b & 15;
  const int w = tid >> 6, lane = tid & 63;
  const int quad = lane >> 4, l16 = lane & 15;

  const int i1 = tid + 256;
  const int r0s = tid >> 3, c0s = tid & 7;
  const int r1s = i1 >> 3, c1s = i1 & 7;
  const int src0 = (c0s ^ (r0s & 7)) * 8;
  const int src1 = (c1s ^ (r1s & 7)) * 8;

  const unsigned short* kbase = k_hm + ((size_t)b << 16);
  const unsigned short* vbase = v_t + ((size_t)b << 16);

  // Q fragments for the 2 l-groups (B-operand, n = l) -- issue BEFORE staging
  u16x8 bq[2][2];
#pragma unroll
  for (int g = 0; g < 2; g++) {
    const unsigned short* qp =
        q_hm + ((size_t)(b * 1024 + l0 + g * 16 + l16) << 6) + quad * 8;
    bq[g][0] = *(const u16x8*)qp;
    bq[g][1] = *(const u16x8*)(qp + 32);
  }
  asm volatile("" ::: "memory");   // pin bq loads before the staging stream

  f32x4 acc[16][2];
#pragma unroll
  for (int j = 0; j < 16; j++)
#pragma unroll
    for (int g = 0; g < 2; g++) { f32x4 z = {0.f, 0.f, 0.f, 0.f}; acc[j][g] = z; }

  // prologue: stage K0..K4 (depth 5)
#pragma unroll
  for (int t = 0; t < 5; t++) {
    gl2lds16(kbase + ((size_t)(t * 64 + r0s) << 6) + src0, &stage[t][tid * 8]);
    gl2lds16(kbase + ((size_t)(t * 64 + r1s) << 6) + src1, &stage[t][i1 * 8]);
  }

  const int myrow = w * 16 + l16;
  const int sw0 = ((quad ^ (l16 & 7)) * 8);
  const int sw1 = (((quad + 4) ^ (l16 & 7)) * 8);

  // ---- phase 1: scores. consume K_j (buf j&7); stage tile j+5 (buf (j+5)&7) ----
#pragma unroll
  for (int j = 0; j < 16; j++) {
    if (j + 5 < 16) {
      gl2lds16(kbase + ((size_t)((j + 5) * 64 + r0s) << 6) + src0,
               &stage[(j + 5) & 7][tid * 8]);
      gl2lds16(kbase + ((size_t)((j + 5) * 64 + r1s) << 6) + src1,
               &stage[(j + 5) & 7][i1 * 8]);
    } else {
      // pipeline handoff: stage V tiles 0..4 for phase 3
      const int vt = j + 5 - 16;
      gl2lds16(vbase + ((size_t)r0s << 10) + vt * 64 + src0,
               &stage[(j + 5) & 7][tid * 8]);
      gl2lds16(vbase + ((size_t)r1s << 10) + vt * 64 + src1,
               &stage[(j + 5) & 7][i1 * 8]);
    }
    asm volatile("s_waitcnt vmcnt(10)" ::: "memory");  // tile j landed; 5 in flight
    __builtin_amdgcn_s_barrier();
    asm volatile("" ::: "memory");
    const unsigned short* kt = &stage[j & 7][myrow * 64];
    u16x8 ak0 = *(const u16x8*)(kt + sw0);
    u16x8 ak1 = *(const u16x8*)(kt + sw1);
    acc[j][0] = mfma16(ak0, bq[0][0], acc[j][0]);
    acc[j][0] = mfma16(ak1, bq[0][1], acc[j][0]);
    acc[j][1] = mfma16(ak0, bq[1][0], acc[j][1]);
    acc[j][1] = mfma16(ak1, bq[1][1], acc[j][1]);
  }

  // ---- phase 2: softmax stats (barriers wait lgkmcnt only; V0..V4 in flight) ----
  float lm0 = -3e38f, lm1 = -3e38f;
#pragma unroll
  for (int j = 0; j < 16; j++)
#pragma unroll
    for (int r = 0; r < 4; r++) {
      lm0 = fmaxf(lm0, acc[j][0][r]);
      lm1 = fmaxf(lm1, acc[j][1][r]);
    }
  lm0 = fmaxf(lm0, __shfl_xor(lm0, 16, 64));
  lm0 = fmaxf(lm0, __shfl_xor(lm0, 32, 64));
  lm1 = fmaxf(lm1, __shfl_xor(lm1, 16, 64));
  lm1 = fmaxf(lm1, __shfl_xor(lm1, 32, 64));
  if (lane < 16) { red_m[w][lane] = lm0; red_m[w][lane + 16] = lm1; }
  asm volatile("s_waitcnt lgkmcnt(0)" ::: "memory");
  __builtin_amdgcn_s_barrier();
  asm volatile("" ::: "memory");
  float m0 = fmaxf(fmaxf(red_m[0][l16], red_m[1][l16]),
                   fmaxf(red_m[2][l16], red_m[3][l16]));
  float m1 = fmaxf(fmaxf(red_m[0][l16 + 16], red_m[1][l16 + 16]),
                   fmaxf(red_m[2][l16 + 16], red_m[3][l16 + 16]));
  float mm = 0.f;
  if (tid < 32)
    mm = fmaxf(fmaxf(red_m[0][tid], red_m[1][tid]),
               fmaxf(red_m[2][tid], red_m[3][tid]));

  float ls0 = 0.f, ls1 = 0.f;
#pragma unroll
  for (int j = 0; j < 16; j++) {
#pragma unroll
    for (int r = 0; r < 4; r++) {
      float e0 = __expf(acc[j][0][r] - m0);
      float e1 = __expf(acc[j][1][r] - m1);
      acc[j][0][r] = e0;
      acc[j][1][r] = e1;
      ls0 += e0;
      ls1 += e1;
    }
  }
  ls0 += __shfl_xor(ls0, 16, 64);
  ls0 += __shfl_xor(ls0, 32, 64);
  ls1 += __shfl_xor(ls1, 16, 64);
  ls1 += __shfl_xor(ls1, 32, 64);
  if (lane < 16) { red_s[w][lane] = ls0; red_s[w][lane + 16] = ls1; }
  asm volatile("s_waitcnt lgkmcnt(0)" ::: "memory");
  __builtin_amdgcn_s_barrier();
  asm volatile("" ::: "memory");
  float rv0 = 1.0f / (red_s[0][l16] + red_s[1][l16] + red_s[2][l16] + red_s[3][l16]);
  float rv1 = 1.0f / (red_s[0][l16 + 16] + red_s[1][l16 + 16] +
                      red_s[2][l16 + 16] + red_s[3][l16 + 16]);
  float ssv = 1.f;
  if (tid < 32)
    ssv = red_s[0][tid] + red_s[1][tid] + red_s[2][tid] + red_s[3][tid];

  // ---- phase 3: PV. consume V_j (buf j&7); stage V_{j+5} (buf (j+5)&7) ----
  {
    uint2 p0 = {cvt_pk_bf16(acc[0][0][0], acc[0][0][1]),
                cvt_pk_bf16(acc[0][0][2], acc[0][0][3])};
    uint2 p1 = {cvt_pk_bf16(acc[0][1][0], acc[0][1][1]),
                cvt_pk_bf16(acc[0][1][2], acc[0][1][3])};
    *(uint2*)&pt[0][l16][w * 16 + quad * 4] = p0;
    *(uint2*)&pt[0][16 + l16][w * 16 + quad * 4] = p1;
  }

  f32x4 oacc0 = {0.f, 0.f, 0.f, 0.f};
  f32x4 oacc1 = {0.f, 0.f, 0.f, 0.f};
#pragma unroll
  for (int j = 0; j < 16; j++) {
    if (j < 11) {
      const int t = j + 5;
      gl2lds16(vbase + ((size_t)r0s << 10) + t * 64 + src0, &stage[t & 7][tid * 8]);
      gl2lds16(vbase + ((size_t)r1s << 10) + t * 64 + src1, &stage[t & 7][i1 * 8]);
      asm volatile("s_waitcnt vmcnt(10) lgkmcnt(0)" ::: "memory");
    } else if (j == 11) {
      asm volatile("s_waitcnt vmcnt(8) lgkmcnt(0)" ::: "memory");
    } else if (j == 12) {
      asm volatile("s_waitcnt vmcnt(6) lgkmcnt(0)" ::: "memory");
    } else if (j == 13) {
      asm volatile("s_waitcnt vmcnt(4) lgkmcnt(0)" ::: "memory");
    } else if (j == 14) {
      asm volatile("s_waitcnt vmcnt(2) lgkmcnt(0)" ::: "memory");
    } else {
      asm volatile("s_waitcnt vmcnt(0) lgkmcnt(0)" ::: "memory");
    }
    __builtin_amdgcn_s_barrier();
    asm volatile("" ::: "memory");
    if (j < 15) {
      const int bf = (j + 1) & 1;
      uint2 p0 = {cvt_pk_bf16(acc[j + 1][0][0], acc[j + 1][0][1]),
                  cvt_pk_bf16(acc[j + 1][0][2], acc[j + 1][0][3])};
      uint2 p1 = {cvt_pk_bf16(acc[j + 1][1][0], acc[j + 1][1][1]),
                  cvt_pk_bf16(acc[j + 1][1][2], acc[j + 1][1][3])};
      *(uint2*)&pt[bf][l16][w * 16 + quad * 4] = p0;
      *(uint2*)&pt[bf][16 + l16][w * 16 + quad * 4] = p1;
    }
    const unsigned short* vt = &stage[j & 7][myrow * 64];
    u16x8 bv0 = *(const u16x8*)(vt + sw0);
    u16x8 bv1 = *(const u16x8*)(vt + sw1);
    u16x8 ap00 = *(const u16x8*)&pt[j & 1][l16][quad * 8];
    u16x8 ap01 = *(const u16x8*)&pt[j & 1][l16][32 + quad * 8];
    u16x8 ap10 = *(const u16x8*)&pt[j & 1][16 + l16][quad * 8];
    u16x8 ap11 = *(const u16x8*)&pt[j & 1][16 + l16][32 + quad * 8];
    oacc0 = mfma16(ap00, bv0, oacc0);
    oacc0 = mfma16(ap01, bv1, oacc0);
    oacc1 = mfma16(ap10, bv0, oacc1);
    oacc1 = mfma16(ap11, bv1, oacc1);
  }

  if (tid < 32) {
    m_ws[b * 1024 + l0 + tid] = mm;
    r_ws[b * 1024 + l0 + tid] = 1.0f / ssv;
  }

#pragma unroll
  for (int r = 0; r < 4; r++) {
    int lr = quad * 4 + r;
    float rr0 = __shfl(rv0, lr, 64);
    float rr1 = __shfl(rv1, lr, 64);
    int t0 = (l0 + lr) * 4 + nb;
    int t1 = (l0 + 16 + lr) * 4 + nb;
    o_h[((size_t)t0 << 10) + h * 64 + w * 16 + l16] = f2bf(oacc0[r] * rr0);
    o_h[((size_t)t1 << 10) + h * 64 + w * 16 + l16] = f2bf(oacc1[r] * rr1);
  }
}

// ---------------- K4: head-averaged attn + sigmoid weights v2 (unchanged) ----------------
__global__ __launch_bounds__(256, 2) void weights_kernel(
    const unsigned short* __restrict__ q_hm, const unsigned short* __restrict__ k_hm,
    const float* __restrict__ m_ws, const float* __restrict__ r_ws,
    float* __restrict__ attn_out, float* __restrict__ sig_out) {
  __shared__ __align__(16) unsigned short qs[4][4096];   // 32 KB
  __shared__ __align__(16) unsigned short ks[4][4096];   // 32 KB
  __shared__ float ml[16][64];
  __shared__ float rl[16][64];
  __shared__ float cl[16][64];

  const int tid = threadIdx.x;
  const int flat = blockIdx.x + (blockIdx.y << 4) + (blockIdx.z << 8);
  const int xcd = flat & 7, local = flat >> 3;           // local: 0..127
  const int nb = xcd >> 1;
  const int idx2 = ((xcd & 1) << 7) + local;             // 0..255
  const int l0 = (idx2 >> 4) << 6;
  const int s0 = (idx2 & 15) << 6;

  const int w = tid >> 6, lane = tid & 63;
  const int quad = lane >> 4, l16 = lane & 15;

  const int i1 = tid + 256;
  const int r0s = tid >> 3, c0s = tid & 7;
  const int r1s = i1 >> 3, c1s = i1 & 7;
  const int src0 = (c0s ^ (r0s & 7)) * 8;
  const int src1 = (c1s ^ (r1s & 7)) * 8;

  {
    int idx = tid * 4;
    int hh = idx >> 6, ii = idx & 63;
    int bb = nb * 16 + hh;
    float4 mv4 = *(const float4*)&m_ws[bb * 1024 + l0 + ii];
    float4 rv4 = *(const float4*)&r_ws[bb * 1024 + l0 + ii];
    *(float4*)&ml[hh][ii] = mv4;
    *(float4*)&rl[hh][ii] = rv4;
    float4 cv4 = {__expf(-mv4.x), __expf(-mv4.y), __expf(-mv4.z), __expf(-mv4.w)};
    *(float4*)&cl[hh][ii] = cv4;
  }

  const int sw0 = ((quad ^ (l16 & 7)) * 8);
  const int sw1 = (((quad + 4) ^ (l16 & 7)) * 8);

  auto stageQK = [&](int h) {
    const int bb = nb * 16 + h;
    const unsigned short* qb = q_hm + ((size_t)(bb * 1024 + l0) << 6);
    const unsigned short* kb = k_hm + ((size_t)(bb * 1024 + s0) << 6);
    const int bf = h & 3;
    gl2lds16(qb + (r0s << 6) + src0, &qs[bf][tid * 8]);
    gl2lds16(qb + (r1s << 6) + src1, &qs[bf][i1 * 8]);
    gl2lds16(kb + (r0s << 6) + src0, &ks[bf][tid * 8]);
    gl2lds16(kb + (r1s << 6) + src1, &ks[bf][i1 * 8]);
  };

  f32x4 accA[4], accS[4];
#pragma unroll
  for (int i = 0; i < 4; i++) {
    f32x4 zz = {0.f, 0.f, 0.f, 0.f};
    accA[i] = zz; accS[i] = zz;
  }

  stageQK(0);
  stageQK(1);
  asm volatile("s_waitcnt lgkmcnt(0)" ::: "memory");  // ml/rl/cl ds_writes done

  auto computeH = [&](int h) {
    const int bf = h & 3;
    const unsigned short* qt = &qs[bf][(w * 16 + l16) * 64];
    u16x8 a0 = *(const u16x8*)(qt + sw0);
    u16x8 a1 = *(const u16x8*)(qt + sw1);
    f32x4 mv = *(const f32x4*)&ml[h][w * 16 + quad * 4];
    f32x4 rv = *(const f32x4*)&rl[h][w * 16 + quad * 4];
    f32x4 cv = *(const f32x4*)&cl[h][w * 16 + quad * 4];
#pragma unroll
    for (int ni = 0; ni < 4; ni++) {
      const unsigned short* kt = &ks[bf][(ni * 16 + l16) * 64];
      u16x8 b0 = *(const u16x8*)(kt + sw0);
      u16x8 b1 = *(const u16x8*)(kt + sw1);
      f32x4 scv = {0.f, 0.f, 0.f, 0.f};
      scv = mfma16(a0, b0, scv);
      scv = mfma16(a1, b1, scv);
#pragma unroll
      for (int r = 0; r < 4; r++) {
        float e = __expf(scv[r] - mv[r]);
        accA[ni][r] += e * rv[r];
        accS[ni][r] += e * __builtin_amdgcn_rcpf(e + cv[r]);
      }
    }
  };

#pragma unroll 1
  for (int h = 0; h < 14; ++h) {
    stageQK(h + 2);
    asm volatile("s_waitcnt vmcnt(8)" ::: "memory");
    __builtin_amdgcn_s_barrier();
    asm volatile("" ::: "memory");
    computeH(h);
  }
  asm volatile("s_waitcnt vmcnt(4)" ::: "memory");
  __builtin_amdgcn_s_barrier();
  asm volatile("" ::: "memory");
  computeH(14);
  asm volatile("s_waitcnt vmcnt(0)" ::: "memory");
  __builtin_amdgcn_s_barrier();
  asm volatile("" ::: "memory");
  computeH(15);

  const float inv_h = 1.0f / 16.0f;
  const int lrow0 = l0 + w * 16;
#pragma unroll
  for (int ni = 0; ni < 4; ni++) {
#pragma unroll
    for (int r = 0; r < 4; r++) {
      int l = lrow0 + quad * 4 + r;
      int s = s0 + ni * 16 + l16;
      size_t idx = ((size_t)nb * 1024 + l) * 1024 + s;
      attn_out[idx] = accA[ni][r] * inv_h;
      sig_out[idx] = accS[ni][r] * inv_h;
    }
  }
}

// ---------------- K5: output projection v3 (round-5 winner, unchanged) ----------------
__global__ __launch_bounds__(256) void out_gemm(
    const unsigned short* __restrict__ o_h, const unsigned short* __restrict__ Wb,
    const float* __restrict__ bias, float* __restrict__ out) {
  __shared__ __align__(16) unsigned short As[3][4096];
  __shared__ __align__(16) unsigned short Bs[3][4096];
  const int tid = threadIdx.x;
  const int bm = blockIdx.x, bn = blockIdx.y;
  const unsigned short* Ag = o_h + (size_t)bm * 128 * 1024;
  const unsigned short* Bg = Wb + (size_t)bn * 128 * 1024;

  const int w = tid >> 6, lane = tid & 63;
  const int wm = w & 1, wn = w >> 1;
  const int quad = lane >> 4, l16 = lane & 15;

  f32x4 acc[4][4];
#pragma unroll
  for (int i = 0; i < 4; i++)
#pragma unroll
    for (int j = 0; j < 4; j++) { f32x4 zz = {0.f, 0.f, 0.f, 0.f}; acc[i][j] = zz; }

  stage_tile(Ag, As[0], tid);
  stage_tile(Bg, Bs[0], tid);

  int cb = 0, sb = 1;
#pragma unroll 1
  for (int kk = 0; kk < 32; kk++) {
    if (kk + 1 < 32) {
      stage_tile(Ag + (kk + 1) * 32, As[sb], tid);
      stage_tile(Bg + (kk + 1) * 32, Bs[sb], tid);
      sb = (sb == 2) ? 0 : sb + 1;
      asm volatile("s_waitcnt vmcnt(4)" ::: "memory");
    } else {
      asm volatile("s_waitcnt vmcnt(0)" ::: "memory");
    }
    __builtin_amdgcn_s_barrier();
    asm volatile("" ::: "memory");
    u16x8 af[4], bfv[4];
#pragma unroll
    for (int mi = 0; mi < 4; mi++) {
      int r = wm * 64 + mi * 16 + l16;
      af[mi] = *(const u16x8*)&As[cb][frag_off(r, quad)];
    }
#pragma unroll
    for (int ni = 0; ni < 4; ni++) {
      int r = wn * 64 + ni * 16 + l16;
      bfv[ni] = *(const u16x8*)&Bs[cb][frag_off(r, quad)];
    }
#pragma unroll
    for (int mi = 0; mi < 4; mi++)
#pragma unroll
      for (int ni = 0; ni < 4; ni++)
        acc[mi][ni] = mfma16(af[mi], bfv[ni], acc[mi][ni]);
    cb = (cb == 2) ? 0 : cb + 1;
  }
#pragma unroll
  for (int ni = 0; ni < 4; ni++) {
    int col = bn * 128 + wn * 64 + ni * 16 + l16;
    float bv = bias[col];
#pragma unroll
    for (int mi = 0; mi < 4; mi++) {
#pragma unroll
      for (int r = 0; r < 4; r++) {
        int t = bm * 128 + wm * 64 + mi * 16 + quad * 4 + r;
        out[(size_t)t * E_DIM + col] = acc[mi][ni][r] + bv;
      }
    }
  }
}

extern "C" void kernel_launch(void* const* d_in, const int* in_sizes, int n_in,
                              void* d_out, int out_size, void* d_ws, size_t ws_size,
                              hipStream_t stream) {
  const float* qin  = (const float*)d_in[0];
  const float* kin  = (const float*)d_in[1];
  const float* vin  = (const float*)d_in[2];
  const float* Wqkv = (const float*)d_in[3];
  const float* bqkv = (const float*)d_in[4];
  const float* Wout = (const float*)d_in[5];
  const float* bout = (const float*)d_in[6];
  float* out      = (float*)d_out;
  float* attn_out = out + 4194304;
  float* sig_out  = out + 8388608;

  unsigned short* q_hm = (unsigned short*)d_ws;      // [64][1024][64] bf16
  unsigned short* k_hm = q_hm + 4194304;             // [64][1024][64]
  unsigned short* v_t  = q_hm + 8388608;             // [64][64][1024]
  unsigned short* o_h  = q_hm + 12582912;            // [4096][1024]
  float* m_ws = (float*)(q_hm + 16777216);           // [64*1024]
  float* r_ws = m_ws + 65536;                        // [64*1024]

  unsigned short* qb = (unsigned short*)(out + 4194304);  // alias: attn/sig region
  unsigned short* kb = qb + 4194304;
  unsigned short* vb = qb + 8388608;
  unsigned short* Wqkvb = o_h;                            // alias: o_h region
  unsigned short* Woutb = v_t;                            // alias: v_t region (cast after attn)

  cast_kernel<<<dim3(2048, 4), 256, 0, stream>>>(
      qin, kin, vin, Wqkv, qb, kb, vb, Wqkvb,
      4194304, 4194304, 4194304, 3145728);
  qkv_gemm<<<dim3(32, 8, 3), 256, 0, stream>>>(qb, kb, vb, Wqkvb, bqkv,
                                               q_hm, k_hm, v_t);
  attn_kernel<<<dim3(32, 64), 256, 0, stream>>>(q_hm, k_hm, v_t, o_h, m_ws, r_ws);
  cast_kernel<<<dim3(512, 1), 256, 0, stream>>>(
      Wout, Wout, Wout, Wout, Woutb, Woutb, Woutb, Woutb,
      1048576, 0, 0, 0);
  weights_kernel<<<dim3(16, 16, 4), 256, 0, stream>>>(q_hm, k_hm, m_ws, r_ws,
                                                      attn_out, sig_out);
  out_gemm<<<dim3(32, 8), 256, 0, stream>>>(o_h, Woutb, bout, out);
}

// Round 7
// 247.542 us; speedup vs baseline: 1.0761x; 1.0098x over previous
//
#include <hip/hip_runtime.h>

// dims
#define L_DIM 1024
#define E_DIM 1024
#define NB 4
#define H_NUM 16
#define HD_DIM 64
#define T_TOK 4096   // L*NB
#define NHB 64       // NB*H_NUM

typedef float f32x4 __attribute__((ext_vector_type(4)));
typedef unsigned short u16x8 __attribute__((ext_vector_type(8)));
typedef unsigned short u16x4 __attribute__((ext_vector_type(4)));
typedef __bf16 bf16x8 __attribute__((ext_vector_type(8)));

__device__ inline unsigned short f2bf(float f) {
  unsigned int u = __builtin_bit_cast(unsigned int, f);
  u += 0x7FFFu + ((u >> 16) & 1u);
  return (unsigned short)(u >> 16);
}
// packed f32x2 -> bf16x2 (RNE), single VALU instruction
__device__ __forceinline__ unsigned int cvt_pk_bf16(float lo, float hi) {
  unsigned int r;
  asm("v_cvt_pk_bf16_f32 %0, %1, %2" : "=v"(r) : "v"(lo), "v"(hi));
  return r;
}
__device__ inline f32x4 mfma16(u16x8 a, u16x8 b, f32x4 c) {
  return __builtin_amdgcn_mfma_f32_16x16x32_bf16(
      __builtin_bit_cast(bf16x8, a), __builtin_bit_cast(bf16x8, b), c, 0, 0, 0);
}

// async global->LDS 16B copy
__device__ __forceinline__ void gl2lds16(const void* g, void* l) {
  auto gp = reinterpret_cast<const __attribute__((address_space(1))) unsigned int*>(
      reinterpret_cast<unsigned long long>(g));
  auto lp = reinterpret_cast<__attribute__((address_space(3))) unsigned int*>(
      static_cast<unsigned int>(reinterpret_cast<unsigned long long>(l)));
  __builtin_amdgcn_global_load_lds(gp, lp, 16, 0, 0);
}

// ---------------- K0: f32 -> bf16 cast (up to 4 arrays per launch) ----------------
__global__ __launch_bounds__(256) void cast_kernel(
    const float* __restrict__ s0, const float* __restrict__ s1,
    const float* __restrict__ s2, const float* __restrict__ s3,
    unsigned short* __restrict__ d0, unsigned short* __restrict__ d1,
    unsigned short* __restrict__ d2, unsigned short* __restrict__ d3,
    int n0, int n1, int n2, int n3) {
  const int y = blockIdx.y;
  const float* s = (y == 0) ? s0 : (y == 1) ? s1 : (y == 2) ? s2 : s3;
  unsigned short* d = (y == 0) ? d0 : (y == 1) ? d1 : (y == 2) ? d2 : d3;
  const int n = (y == 0) ? n0 : (y == 1) ? n1 : (y == 2) ? n2 : n3;
  int idx = (blockIdx.x * 256 + threadIdx.x) * 8;
  const int stride = gridDim.x * 256 * 8;
  for (; idx < n; idx += stride) {
    float4 a = *(const float4*)(s + idx);
    float4 b = *(const float4*)(s + idx + 4);
    u16x8 o = {f2bf(a.x), f2bf(a.y), f2bf(a.z), f2bf(a.w),
               f2bf(b.x), f2bf(b.y), f2bf(b.z), f2bf(b.w)};
    *(u16x8*)(d + idx) = o;
  }
}

// ---- shared GEMM staging: 128 rows x 32 k bf16 tile (8 KB), swizzled ----
__device__ __forceinline__ void stage_tile(const unsigned short* __restrict__ g,
                                           unsigned short* lbuf, int tid) {
  const int r = tid >> 2, c = tid & 3;
  const int sc = c ^ ((r ^ (r >> 2)) & 3);
  gl2lds16(g + (size_t)r * 1024 + sc * 8, lbuf + tid * 8);
  const int r2 = r + 64;
  gl2lds16(g + (size_t)r2 * 1024 + sc * 8, lbuf + (tid + 256) * 8);
}
__device__ __forceinline__ int frag_off(int r, int q) {
  return r * 32 + ((q ^ ((r ^ (r >> 2)) & 3)) << 3);
}

// ---------------- K1: packed QKV projection v3 (round-5 winner, unchanged) ----------------
__global__ __launch_bounds__(256) void qkv_gemm(
    const unsigned short* __restrict__ qb, const unsigned short* __restrict__ kb,
    const unsigned short* __restrict__ vb, const unsigned short* __restrict__ Wb,
    const float* __restrict__ bias, unsigned short* __restrict__ q_hm,
    unsigned short* __restrict__ k_hm, unsigned short* __restrict__ v_t) {
  __shared__ __align__(16) unsigned short As[3][4096];   // 24 KB
  __shared__ __align__(16) unsigned short Bs[3][4096];   // 24 KB
  const int tid = threadIdx.x;
  const int bm = blockIdx.x, bn = blockIdx.y, z = blockIdx.z;
  const unsigned short* Ag = ((z == 0) ? qb : (z == 1) ? kb : vb) + (size_t)bm * 128 * 1024;
  const unsigned short* Bg = Wb + (size_t)z * 1048576 + (size_t)bn * 128 * 1024;
  const float* bc = bias + z * E_DIM;

  const int w = tid >> 6, lane = tid & 63;
  const int wm = w & 1, wn = w >> 1;
  const int quad = lane >> 4, l16 = lane & 15;

  f32x4 acc[4][4];
#pragma unroll
  for (int i = 0; i < 4; i++)
#pragma unroll
    for (int j = 0; j < 4; j++) { f32x4 zz = {0.f, 0.f, 0.f, 0.f}; acc[i][j] = zz; }

  stage_tile(Ag, As[0], tid);
  stage_tile(Bg, Bs[0], tid);

  int cb = 0, sb = 1;
#pragma unroll 1
  for (int kk = 0; kk < 32; kk++) {
    if (kk + 1 < 32) {
      stage_tile(Ag + (kk + 1) * 32, As[sb], tid);
      stage_tile(Bg + (kk + 1) * 32, Bs[sb], tid);
      sb = (sb == 2) ? 0 : sb + 1;
      asm volatile("s_waitcnt vmcnt(4)" ::: "memory");   // tile kk landed; kk+1 in flight
    } else {
      asm volatile("s_waitcnt vmcnt(0)" ::: "memory");
    }
    __builtin_amdgcn_s_barrier();
    asm volatile("" ::: "memory");
    u16x8 af[4], bfv[4];
#pragma unroll
    for (int mi = 0; mi < 4; mi++) {
      int r = wm * 64 + mi * 16 + l16;
      af[mi] = *(const u16x8*)&As[cb][frag_off(r, quad)];
    }
#pragma unroll
    for (int ni = 0; ni < 4; ni++) {
      int r = wn * 64 + ni * 16 + l16;
      bfv[ni] = *(const u16x8*)&Bs[cb][frag_off(r, quad)];
    }
#pragma unroll
    for (int mi = 0; mi < 4; mi++)
#pragma unroll
      for (int ni = 0; ni < 4; ni++)
        acc[mi][ni] = mfma16(af[mi], bfv[ni], acc[mi][ni]);
    cb = (cb == 2) ? 0 : cb + 1;
  }
#pragma unroll
  for (int ni = 0; ni < 4; ni++) {
    int col = bn * 128 + wn * 64 + ni * 16 + l16;
    float bv = bc[col];
    int h = col >> 6, d = col & 63;
#pragma unroll
    for (int mi = 0; mi < 4; mi++) {
#pragma unroll
      for (int r = 0; r < 4; r++) {
        int t = bm * 128 + wm * 64 + mi * 16 + quad * 4 + r;
        float v = acc[mi][ni][r] + bv;
        int nb = t & 3, pos = t >> 2;
        if (z == 0) {
          v *= 0.125f;
          q_hm[(size_t)((nb * 16 + h) * 1024 + pos) * 64 + d] = f2bf(v);
        } else if (z == 1) {
          k_hm[(size_t)((nb * 16 + h) * 1024 + pos) * 64 + d] = f2bf(v);
        } else {
          v_t[(size_t)((nb * 16 + h) * 64 + d) * 1024 + pos] = f2bf(v);
        }
      }
    }
  }
}

// ---------------- K3: attention core v7: 2 tiles per barrier ----------------
// 34 -> 18 sync points. Stage ring: 6 bufs, pair-depth-1 (safe: stage of pair
// i+1, issued after barrier i-1, overwrites pair i-2 whose reads retired before
// its waves reached barrier i-1). pt: 4 slots (tile t -> slot t%4; previous
// occupant t-4 read a full barrier before the write). LDS 67.6 KB -> 2 blk/CU.
__global__ __launch_bounds__(256, 2) void attn_kernel(
    const unsigned short* __restrict__ q_hm, const unsigned short* __restrict__ k_hm,
    const unsigned short* __restrict__ v_t, unsigned short* __restrict__ o_h,
    float* __restrict__ m_ws, float* __restrict__ r_ws) {
  __shared__ __align__(16) unsigned short stage[6][4096];   // 6 x 64x64 bf16 tiles
  __shared__ __align__(16) unsigned short pt[4][32][68];    // 4-slot rotating P tiles
  __shared__ float red_m[4][32];
  __shared__ float red_s[4][32];

  const int tid = threadIdx.x;
  // XCD-bijective swizzle: linear id -> (xcd, local) -> contiguous heads per XCD
  const int flat = blockIdx.x + (blockIdx.y << 5);   // 0..2047
  const int nf = (flat & 7) * 256 + (flat >> 3);
  const int l0 = (nf & 31) * 32;
  const int b = nf >> 5;
  const int nb = b >> 4, h = b & 15;
  const int w = tid >> 6, lane = tid & 63;
  const int quad = lane >> 4, l16 = lane & 15;

  const int i1 = tid + 256;
  const int r0s = tid >> 3, c0s = tid & 7;
  const int r1s = i1 >> 3, c1s = i1 & 7;
  const int src0 = (c0s ^ (r0s & 7)) * 8;
  const int src1 = (c1s ^ (r1s & 7)) * 8;

  const unsigned short* kbase = k_hm + ((size_t)b << 16);
  const unsigned short* vbase = v_t + ((size_t)b << 16);

  // Q fragments for the 2 l-groups (B-operand, n = l) -- issue BEFORE staging
  u16x8 bq[2][2];
#pragma unroll
  for (int g = 0; g < 2; g++) {
    const unsigned short* qp =
        q_hm + ((size_t)(b * 1024 + l0 + g * 16 + l16) << 6) + quad * 8;
    bq[g][0] = *(const u16x8*)qp;
    bq[g][1] = *(const u16x8*)(qp + 32);
  }
  asm volatile("" ::: "memory");   // pin bq loads before the staging stream

  f32x4 acc[16][2];
#pragma unroll
  for (int j = 0; j < 16; j++)
#pragma unroll
    for (int g = 0; g < 2; g++) { f32x4 z = {0.f, 0.f, 0.f, 0.f}; acc[j][g] = z; }

  // prologue: stage K pairs 0,1 (tiles 0..3 -> bufs 0..3)
#pragma unroll
  for (int t = 0; t < 4; t++) {
    gl2lds16(kbase + ((size_t)(t * 64 + r0s) << 6) + src0, &stage[t][tid * 8]);
    gl2lds16(kbase + ((size_t)(t * 64 + r1s) << 6) + src1, &stage[t][i1 * 8]);
  }

  const int myrow = w * 16 + l16;
  const int sw0 = ((quad ^ (l16 & 7)) * 8);
  const int sw1 = (((quad + 4) ^ (l16 & 7)) * 8);

  // ---- phase 1: scores, 2 K-tiles per barrier (8 iterations) ----
#pragma unroll
  for (int i = 0; i < 8; i++) {
    if (i >= 1) {
      const int t0 = 2 * i + 2, t1 = 2 * i + 3;   // pair i+1
      if (t0 < 16) {
        gl2lds16(kbase + ((size_t)(t0 * 64 + r0s) << 6) + src0, &stage[t0 % 6][tid * 8]);
        gl2lds16(kbase + ((size_t)(t0 * 64 + r1s) << 6) + src1, &stage[t0 % 6][i1 * 8]);
        gl2lds16(kbase + ((size_t)(t1 * 64 + r0s) << 6) + src0, &stage[t1 % 6][tid * 8]);
        gl2lds16(kbase + ((size_t)(t1 * 64 + r1s) << 6) + src1, &stage[t1 % 6][i1 * 8]);
      } else {
        // pipeline handoff: V tiles 0,1 (global tiles 16,17)
        const int v0 = t0 - 16, v1 = t1 - 16;
        gl2lds16(vbase + ((size_t)r0s << 10) + v0 * 64 + src0, &stage[t0 % 6][tid * 8]);
        gl2lds16(vbase + ((size_t)r1s << 10) + v0 * 64 + src1, &stage[t0 % 6][i1 * 8]);
        gl2lds16(vbase + ((size_t)r0s << 10) + v1 * 64 + src0, &stage[t1 % 6][tid * 8]);
        gl2lds16(vbase + ((size_t)r1s << 10) + v1 * 64 + src1, &stage[t1 % 6][i1 * 8]);
      }
    }
    asm volatile("s_waitcnt vmcnt(4)" ::: "memory");   // pair i landed; 1 pair in flight
    __builtin_amdgcn_s_barrier();
    asm volatile("" ::: "memory");
    const int c0 = 2 * i, c1 = 2 * i + 1;
    const unsigned short* kt0 = &stage[c0 % 6][myrow * 64];
    const unsigned short* kt1 = &stage[c1 % 6][myrow * 64];
    u16x8 a00 = *(const u16x8*)(kt0 + sw0);
    u16x8 a01 = *(const u16x8*)(kt0 + sw1);
    u16x8 a10 = *(const u16x8*)(kt1 + sw0);
    u16x8 a11 = *(const u16x8*)(kt1 + sw1);
    acc[c0][0] = mfma16(a00, bq[0][0], acc[c0][0]);
    acc[c0][0] = mfma16(a01, bq[0][1], acc[c0][0]);
    acc[c0][1] = mfma16(a00, bq[1][0], acc[c0][1]);
    acc[c0][1] = mfma16(a01, bq[1][1], acc[c0][1]);
    acc[c1][0] = mfma16(a10, bq[0][0], acc[c1][0]);
    acc[c1][0] = mfma16(a11, bq[0][1], acc[c1][0]);
    acc[c1][1] = mfma16(a10, bq[1][0], acc[c1][1]);
    acc[c1][1] = mfma16(a11, bq[1][1], acc[c1][1]);
  }

  // stage V pair 9 (tiles 18,19 = V-local 2,3 -> bufs 0,1) under the softmax.
  // bufs 0,1 held tiles 12,13 (read at phase-1 iter 6; retired before barrier 7).
  gl2lds16(vbase + ((size_t)r0s << 10) + 2 * 64 + src0, &stage[0][tid * 8]);
  gl2lds16(vbase + ((size_t)r1s << 10) + 2 * 64 + src1, &stage[0][i1 * 8]);
  gl2lds16(vbase + ((size_t)r0s << 10) + 3 * 64 + src0, &stage[1][tid * 8]);
  gl2lds16(vbase + ((size_t)r1s << 10) + 3 * 64 + src1, &stage[1][i1 * 8]);

  // ---- phase 2: softmax stats (barriers wait lgkmcnt only; V pairs 8,9 in flight) ----
  float lm0 = -3e38f, lm1 = -3e38f;
#pragma unroll
  for (int j = 0; j < 16; j++)
#pragma unroll
    for (int r = 0; r < 4; r++) {
      lm0 = fmaxf(lm0, acc[j][0][r]);
      lm1 = fmaxf(lm1, acc[j][1][r]);
    }
  lm0 = fmaxf(lm0, __shfl_xor(lm0, 16, 64));
  lm0 = fmaxf(lm0, __shfl_xor(lm0, 32, 64));
  lm1 = fmaxf(lm1, __shfl_xor(lm1, 16, 64));
  lm1 = fmaxf(lm1, __shfl_xor(lm1, 32, 64));
  if (lane < 16) { red_m[w][lane] = lm0; red_m[w][lane + 16] = lm1; }
  asm volatile("s_waitcnt lgkmcnt(0)" ::: "memory");
  __builtin_amdgcn_s_barrier();
  asm volatile("" ::: "memory");
  float m0 = fmaxf(fmaxf(red_m[0][l16], red_m[1][l16]),
                   fmaxf(red_m[2][l16], red_m[3][l16]));
  float m1 = fmaxf(fmaxf(red_m[0][l16 + 16], red_m[1][l16 + 16]),
                   fmaxf(red_m[2][l16 + 16], red_m[3][l16 + 16]));
  float mm = 0.f;
  if (tid < 32)
    mm = fmaxf(fmaxf(red_m[0][tid], red_m[1][tid]),
               fmaxf(red_m[2][tid], red_m[3][tid]));

  float ls0 = 0.f, ls1 = 0.f;
#pragma unroll
  for (int j = 0; j < 16; j++) {
#pragma unroll
    for (int r = 0; r < 4; r++) {
      float e0 = __expf(acc[j][0][r] - m0);
      float e1 = __expf(acc[j][1][r] - m1);
      acc[j][0][r] = e0;
      acc[j][1][r] = e1;
      ls0 += e0;
      ls1 += e1;
    }
  }
  ls0 += __shfl_xor(ls0, 16, 64);
  ls0 += __shfl_xor(ls0, 32, 64);
  ls1 += __shfl_xor(ls1, 16, 64);
  ls1 += __shfl_xor(ls1, 32, 64);
  if (lane < 16) { red_s[w][lane] = ls0; red_s[w][lane + 16] = ls1; }
  asm volatile("s_waitcnt lgkmcnt(0)" ::: "memory");
  __builtin_amdgcn_s_barrier();
  asm volatile("" ::: "memory");
  float rv0 = 1.0f / (red_s[0][l16] + red_s[1][l16] + red_s[2][l16] + red_s[3][l16]);
  float rv1 = 1.0f / (red_s[0][l16 + 16] + red_s[1][l16 + 16] +
                      red_s[2][l16 + 16] + red_s[3][l16 + 16]);
  float ssv = 1.f;
  if (tid < 32)
    ssv = red_s[0][tid] + red_s[1][tid] + red_s[2][tid] + red_s[3][tid];

  // ---- phase 3: PV, 2 V-tiles per barrier (8 iterations) ----
  // pre-loop: P tiles 0,1 -> pt slots 0,1 (drained by iter-0 lgkmcnt)
  {
    uint2 p00 = {cvt_pk_bf16(acc[0][0][0], acc[0][0][1]),
                 cvt_pk_bf16(acc[0][0][2], acc[0][0][3])};
    uint2 p01 = {cvt_pk_bf16(acc[0][1][0], acc[0][1][1]),
                 cvt_pk_bf16(acc[0][1][2], acc[0][1][3])};
    *(uint2*)&pt[0][l16][w * 16 + quad * 4] = p00;
    *(uint2*)&pt[0][16 + l16][w * 16 + quad * 4] = p01;
    uint2 p10 = {cvt_pk_bf16(acc[1][0][0], acc[1][0][1]),
                 cvt_pk_bf16(acc[1][0][2], acc[1][0][3])};
    uint2 p11 = {cvt_pk_bf16(acc[1][1][0], acc[1][1][1]),
                 cvt_pk_bf16(acc[1][1][2], acc[1][1][3])};
    *(uint2*)&pt[1][l16][w * 16 + quad * 4] = p10;
    *(uint2*)&pt[1][16 + l16][w * 16 + quad * 4] = p11;
  }

  f32x4 oacc0 = {0.f, 0.f, 0.f, 0.f};
  f32x4 oacc1 = {0.f, 0.f, 0.f, 0.f};
#pragma unroll
  for (int i = 0; i < 8; i++) {
    if (i >= 1 && i <= 6) {
      // stage V pair 9+i (V-local tiles 2i+2, 2i+3)
      const int v0 = 2 * i + 2, v1 = 2 * i + 3;
      const int b0 = (v0 + 16) % 6, b1 = (v1 + 16) % 6;
      gl2lds16(vbase + ((size_t)r0s << 10) + v0 * 64 + src0, &stage[b0][tid * 8]);
      gl2lds16(vbase + ((size_t)r1s << 10) + v0 * 64 + src1, &stage[b0][i1 * 8]);
      gl2lds16(vbase + ((size_t)r0s << 10) + v1 * 64 + src0, &stage[b1][tid * 8]);
      gl2lds16(vbase + ((size_t)r1s << 10) + v1 * 64 + src1, &stage[b1][i1 * 8]);
    }
    if (i < 7) {
      asm volatile("s_waitcnt vmcnt(4) lgkmcnt(0)" ::: "memory");
    } else {
      asm volatile("s_waitcnt vmcnt(0) lgkmcnt(0)" ::: "memory");
    }
    __builtin_amdgcn_s_barrier();
    asm volatile("" ::: "memory");
    if (i < 7) {
      const int tA = 2 * i + 2, tB = 2 * i + 3;
      uint2 pA0 = {cvt_pk_bf16(acc[tA][0][0], acc[tA][0][1]),
                   cvt_pk_bf16(acc[tA][0][2], acc[tA][0][3])};
      uint2 pA1 = {cvt_pk_bf16(acc[tA][1][0], acc[tA][1][1]),
                   cvt_pk_bf16(acc[tA][1][2], acc[tA][1][3])};
      *(uint2*)&pt[tA % 4][l16][w * 16 + quad * 4] = pA0;
      *(uint2*)&pt[tA % 4][16 + l16][w * 16 + quad * 4] = pA1;
      uint2 pB0 = {cvt_pk_bf16(acc[tB][0][0], acc[tB][0][1]),
                   cvt_pk_bf16(acc[tB][0][2], acc[tB][0][3])};
      uint2 pB1 = {cvt_pk_bf16(acc[tB][1][0], acc[tB][1][1]),
                   cvt_pk_bf16(acc[tB][1][2], acc[tB][1][3])};
      *(uint2*)&pt[tB % 4][l16][w * 16 + quad * 4] = pB0;
      *(uint2*)&pt[tB % 4][16 + l16][w * 16 + quad * 4] = pB1;
    }
    const int cA = 2 * i, cB = 2 * i + 1;           // V-local tiles this iteration
    const unsigned short* vt0 = &stage[(cA + 16) % 6][myrow * 64];
    const unsigned short* vt1 = &stage[(cB + 16) % 6][myrow * 64];
    u16x8 bvA0 = *(const u16x8*)(vt0 + sw0);
    u16x8 bvA1 = *(const u16x8*)(vt0 + sw1);
    u16x8 bvB0 = *(const u16x8*)(vt1 + sw0);
    u16x8 bvB1 = *(const u16x8*)(vt1 + sw1);
    u16x8 apA00 = *(const u16x8*)&pt[cA % 4][l16][quad * 8];
    u16x8 apA01 = *(const u16x8*)&pt[cA % 4][l16][32 + quad * 8];
    u16x8 apA10 = *(const u16x8*)&pt[cA % 4][16 + l16][quad * 8];
    u16x8 apA11 = *(const u16x8*)&pt[cA % 4][16 + l16][32 + quad * 8];
    u16x8 apB00 = *(const u16x8*)&pt[cB % 4][l16][quad * 8];
    u16x8 apB01 = *(const u16x8*)&pt[cB % 4][l16][32 + quad * 8];
    u16x8 apB10 = *(const u16x8*)&pt[cB % 4][16 + l16][quad * 8];
    u16x8 apB11 = *(const u16x8*)&pt[cB % 4][16 + l16][32 + quad * 8];
    oacc0 = mfma16(apA00, bvA0, oacc0);
    oacc0 = mfma16(apA01, bvA1, oacc0);
    oacc0 = mfma16(apB00, bvB0, oacc0);
    oacc0 = mfma16(apB01, bvB1, oacc0);
    oacc1 = mfma16(apA10, bvA0, oacc1);
    oacc1 = mfma16(apA11, bvA1, oacc1);
    oacc1 = mfma16(apB10, bvB0, oacc1);
    oacc1 = mfma16(apB11, bvB1, oacc1);
  }

  if (tid < 32) {
    m_ws[b * 1024 + l0 + tid] = mm;
    r_ws[b * 1024 + l0 + tid] = 1.0f / ssv;
  }

#pragma unroll
  for (int r = 0; r < 4; r++) {
    int lr = quad * 4 + r;
    float rr0 = __shfl(rv0, lr, 64);
    float rr1 = __shfl(rv1, lr, 64);
    int t0 = (l0 + lr) * 4 + nb;
    int t1 = (l0 + 16 + lr) * 4 + nb;
    o_h[((size_t)t0 << 10) + h * 64 + w * 16 + l16] = f2bf(oacc0[r] * rr0);
    o_h[((size_t)t1 << 10) + h * 64 + w * 16 + l16] = f2bf(oacc1[r] * rr1);
  }
}

// ---------------- K4: head-averaged attn + sigmoid weights v2 (unchanged) ----------------
__global__ __launch_bounds__(256, 2) void weights_kernel(
    const unsigned short* __restrict__ q_hm, const unsigned short* __restrict__ k_hm,
    const float* __restrict__ m_ws, const float* __restrict__ r_ws,
    float* __restrict__ attn_out, float* __restrict__ sig_out) {
  __shared__ __align__(16) unsigned short qs[4][4096];   // 32 KB
  __shared__ __align__(16) unsigned short ks[4][4096];   // 32 KB
  __shared__ float ml[16][64];
  __shared__ float rl[16][64];
  __shared__ float cl[16][64];

  const int tid = threadIdx.x;
  const int flat = blockIdx.x + (blockIdx.y << 4) + (blockIdx.z << 8);
  const int xcd = flat & 7, local = flat >> 3;           // local: 0..127
  const int nb = xcd >> 1;
  const int idx2 = ((xcd & 1) << 7) + local;             // 0..255
  const int l0 = (idx2 >> 4) << 6;
  const int s0 = (idx2 & 15) << 6;

  const int w = tid >> 6, lane = tid & 63;
  const int quad = lane >> 4, l16 = lane & 15;

  const int i1 = tid + 256;
  const int r0s = tid >> 3, c0s = tid & 7;
  const int r1s = i1 >> 3, c1s = i1 & 7;
  const int src0 = (c0s ^ (r0s & 7)) * 8;
  const int src1 = (c1s ^ (r1s & 7)) * 8;

  {
    int idx = tid * 4;
    int hh = idx >> 6, ii = idx & 63;
    int bb = nb * 16 + hh;
    float4 mv4 = *(const float4*)&m_ws[bb * 1024 + l0 + ii];
    float4 rv4 = *(const float4*)&r_ws[bb * 1024 + l0 + ii];
    *(float4*)&ml[hh][ii] = mv4;
    *(float4*)&rl[hh][ii] = rv4;
    float4 cv4 = {__expf(-mv4.x), __expf(-mv4.y), __expf(-mv4.z), __expf(-mv4.w)};
    *(float4*)&cl[hh][ii] = cv4;
  }

  const int sw0 = ((quad ^ (l16 & 7)) * 8);
  const int sw1 = (((quad + 4) ^ (l16 & 7)) * 8);

  auto stageQK = [&](int h) {
    const int bb = nb * 16 + h;
    const unsigned short* qb = q_hm + ((size_t)(bb * 1024 + l0) << 6);
    const unsigned short* kb = k_hm + ((size_t)(bb * 1024 + s0) << 6);
    const int bf = h & 3;
    gl2lds16(qb + (r0s << 6) + src0, &qs[bf][tid * 8]);
    gl2lds16(qb + (r1s << 6) + src1, &qs[bf][i1 * 8]);
    gl2lds16(kb + (r0s << 6) + src0, &ks[bf][tid * 8]);
    gl2lds16(kb + (r1s << 6) + src1, &ks[bf][i1 * 8]);
  };

  f32x4 accA[4], accS[4];
#pragma unroll
  for (int i = 0; i < 4; i++) {
    f32x4 zz = {0.f, 0.f, 0.f, 0.f};
    accA[i] = zz; accS[i] = zz;
  }

  stageQK(0);
  stageQK(1);
  asm volatile("s_waitcnt lgkmcnt(0)" ::: "memory");  // ml/rl/cl ds_writes done

  auto computeH = [&](int h) {
    const int bf = h & 3;
    const unsigned short* qt = &qs[bf][(w * 16 + l16) * 64];
    u16x8 a0 = *(const u16x8*)(qt + sw0);
    u16x8 a1 = *(const u16x8*)(qt + sw1);
    f32x4 mv = *(const f32x4*)&ml[h][w * 16 + quad * 4];
    f32x4 rv = *(const f32x4*)&rl[h][w * 16 + quad * 4];
    f32x4 cv = *(const f32x4*)&cl[h][w * 16 + quad * 4];
#pragma unroll
    for (int ni = 0; ni < 4; ni++) {
      const unsigned short* kt = &ks[bf][(ni * 16 + l16) * 64];
      u16x8 b0 = *(const u16x8*)(kt + sw0);
      u16x8 b1 = *(const u16x8*)(kt + sw1);
      f32x4 scv = {0.f, 0.f, 0.f, 0.f};
      scv = mfma16(a0, b0, scv);
      scv = mfma16(a1, b1, scv);
#pragma unroll
      for (int r = 0; r < 4; r++) {
        float e = __expf(scv[r] - mv[r]);
        accA[ni][r] += e * rv[r];
        accS[ni][r] += e * __builtin_amdgcn_rcpf(e + cv[r]);
      }
    }
  };

#pragma unroll 1
  for (int h = 0; h < 14; ++h) {
    stageQK(h + 2);
    asm volatile("s_waitcnt vmcnt(8)" ::: "memory");
    __builtin_amdgcn_s_barrier();
    asm volatile("" ::: "memory");
    computeH(h);
  }
  asm volatile("s_waitcnt vmcnt(4)" ::: "memory");
  __builtin_amdgcn_s_barrier();
  asm volatile("" ::: "memory");
  computeH(14);
  asm volatile("s_waitcnt vmcnt(0)" ::: "memory");
  __builtin_amdgcn_s_barrier();
  asm volatile("" ::: "memory");
  computeH(15);

  const float inv_h = 1.0f / 16.0f;
  const int lrow0 = l0 + w * 16;
#pragma unroll
  for (int ni = 0; ni < 4; ni++) {
#pragma unroll
    for (int r = 0; r < 4; r++) {
      int l = lrow0 + quad * 4 + r;
      int s = s0 + ni * 16 + l16;
      size_t idx = ((size_t)nb * 1024 + l) * 1024 + s;
      attn_out[idx] = accA[ni][r] * inv_h;
      sig_out[idx] = accS[ni][r] * inv_h;
    }
  }
}

// ---------------- K5: output projection v3 (round-5 winner, unchanged) ----------------
__global__ __launch_bounds__(256) void out_gemm(
    const unsigned short* __restrict__ o_h, const unsigned short* __restrict__ Wb,
    const float* __restrict__ bias, float* __restrict__ out) {
  __shared__ __align__(16) unsigned short As[3][4096];
  __shared__ __align__(16) unsigned short Bs[3][4096];
  const int tid = threadIdx.x;
  const int bm = blockIdx.x, bn = blockIdx.y;
  const unsigned short* Ag = o_h + (size_t)bm * 128 * 1024;
  const unsigned short* Bg = Wb + (size_t)bn * 128 * 1024;

  const int w = tid >> 6, lane = tid & 63;
  const int wm = w & 1, wn = w >> 1;
  const int quad = lane >> 4, l16 = lane & 15;

  f32x4 acc[4][4];
#pragma unroll
  for (int i = 0; i < 4; i++)
#pragma unroll
    for (int j = 0; j < 4; j++) { f32x4 zz = {0.f, 0.f, 0.f, 0.f}; acc[i][j] = zz; }

  stage_tile(Ag, As[0], tid);
  stage_tile(Bg, Bs[0], tid);

  int cb = 0, sb = 1;
#pragma unroll 1
  for (int kk = 0; kk < 32; kk++) {
    if (kk + 1 < 32) {
      stage_tile(Ag + (kk + 1) * 32, As[sb], tid);
      stage_tile(Bg + (kk + 1) * 32, Bs[sb], tid);
      sb = (sb == 2) ? 0 : sb + 1;
      asm volatile("s_waitcnt vmcnt(4)" ::: "memory");
    } else {
      asm volatile("s_waitcnt vmcnt(0)" ::: "memory");
    }
    __builtin_amdgcn_s_barrier();
    asm volatile("" ::: "memory");
    u16x8 af[4], bfv[4];
#pragma unroll
    for (int mi = 0; mi < 4; mi++) {
      int r = wm * 64 + mi * 16 + l16;
      af[mi] = *(const u16x8*)&As[cb][frag_off(r, quad)];
    }
#pragma unroll
    for (int ni = 0; ni < 4; ni++) {
      int r = wn * 64 + ni * 16 + l16;
      bfv[ni] = *(const u16x8*)&Bs[cb][frag_off(r, quad)];
    }
#pragma unroll
    for (int mi = 0; mi < 4; mi++)
#pragma unroll
      for (int ni = 0; ni < 4; ni++)
        acc[mi][ni] = mfma16(af[mi], bfv[ni], acc[mi][ni]);
    cb = (cb == 2) ? 0 : cb + 1;
  }
#pragma unroll
  for (int ni = 0; ni < 4; ni++) {
    int col = bn * 128 + wn * 64 + ni * 16 + l16;
    float bv = bias[col];
#pragma unroll
    for (int mi = 0; mi < 4; mi++) {
#pragma unroll
      for (int r = 0; r < 4; r++) {
        int t = bm * 128 + wm * 64 + mi * 16 + quad * 4 + r;
        out[(size_t)t * E_DIM + col] = acc[mi][ni][r] + bv;
      }
    }
  }
}

extern "C" void kernel_launch(void* const* d_in, const int* in_sizes, int n_in,
                              void* d_out, int out_size, void* d_ws, size_t ws_size,
                              hipStream_t stream) {
  const float* qin  = (const float*)d_in[0];
  const float* kin  = (const float*)d_in[1];
  const float* vin  = (const float*)d_in[2];
  const float* Wqkv = (const float*)d_in[3];
  const float* bqkv = (const float*)d_in[4];
  const float* Wout = (const float*)d_in[5];
  const float* bout = (const float*)d_in[6];
  float* out      = (float*)d_out;
  float* attn_out = out + 4194304;
  float* sig_out  = out + 8388608;

  unsigned short* q_hm = (unsigned short*)d_ws;      // [64][1024][64] bf16
  unsigned short* k_hm = q_hm + 4194304;             // [64][1024][64]
  unsigned short* v_t  = q_hm + 8388608;             // [64][64][1024]
  unsigned short* o_h  = q_hm + 12582912;            // [4096][1024]
  float* m_ws = (float*)(q_hm + 16777216);           // [64*1024]
  float* r_ws = m_ws + 65536;                        // [64*1024]

  unsigned short* qb = (unsigned short*)(out + 4194304);  // alias: attn/sig region
  unsigned short* kb = qb + 4194304;
  unsigned short* vb = qb + 8388608;
  unsigned short* Wqkvb = o_h;                            // alias: o_h region
  unsigned short* Woutb = v_t;                            // alias: v_t region (cast after attn)

  cast_kernel<<<dim3(2048, 4), 256, 0, stream>>>(
      qin, kin, vin, Wqkv, qb, kb, vb, Wqkvb,
      4194304, 4194304, 4194304, 3145728);
  qkv_gemm<<<dim3(32, 8, 3), 256, 0, stream>>>(qb, kb, vb, Wqkvb, bqkv,
                                               q_hm, k_hm, v_t);
  attn_kernel<<<dim3(32, 64), 256, 0, stream>>>(q_hm, k_hm, v_t, o_h, m_ws, r_ws);
  cast_kernel<<<dim3(512, 1), 256, 0, stream>>>(
      Wout, Wout, Wout, Wout, Woutb, Woutb, Woutb, Woutb,
      1048576, 0, 0, 0);
  weights_kernel<<<dim3(16, 16, 4), 256, 0, stream>>>(q_hm, k_hm, m_ws, r_ws,
                                                      attn_out, sig_out);
  out_gemm<<<dim3(32, 8), 256, 0, stream>>>(o_h, Woutb, bout, out);
}